// Round 9
// baseline (845.134 us; speedup 1.0000x reference)
//
#include <hip/hip_runtime.h>

#define NCC 200000
#define NPRR 100000
#define NEE 500000
#define NBB 200000

typedef __attribute__((ext_vector_type(8))) short bf16x8;
typedef __attribute__((ext_vector_type(16))) float f32x16;

__device__ __forceinline__ float b2f(unsigned short u){ return __uint_as_float(((unsigned)u)<<16); }
__device__ __forceinline__ unsigned short f2b(float f){
  unsigned x = __float_as_uint(f);
  return (unsigned short)((x + 0x7fffu + ((x>>16)&1u)) >> 16);
}

// ---- WA prep ----
__global__ __launch_bounds__(256) void wa_prep(const float* __restrict__ W,
    const float* __restrict__ bias,
    const float* __restrict__ attA, const float* __restrict__ attB,
    float* __restrict__ WA)
{
  int tid = threadIdx.x;
  for (int task = tid; task < 2*17*8; task += 256) {
    int set = task / 136, rem = task % 136;
    int k = rem >> 3, h = rem & 7;
    const float* att = set ? attB : attA;
    const float* row = (k < 16) ? (W + k*256) : bias;
    float acc = 0.f;
    for (int d = 0; d < 32; d++) acc = fmaf(row[h*32+d], att[h*32+d], acc);
    WA[task] = acc;
  }
}

// ---- scores ----
__global__ __launch_bounds__(256) void score_kernel(const float* __restrict__ X,
    const float* __restrict__ WA, float* __restrict__ sA, float* __restrict__ sB, int N)
{
  __shared__ float wa[272];
  int tid = threadIdx.x;
  for (int i = tid; i < 272; i += 256) wa[i] = WA[i];
  __syncthreads();
  int n = blockIdx.x*256 + tid;
  if (n >= N) return;
  const float4* px = (const float4*)(X + (long long)n*16);
  float4 v0 = px[0], v1 = px[1], v2 = px[2], v3 = px[3];
  float x[16] = {v0.x,v0.y,v0.z,v0.w, v1.x,v1.y,v1.z,v1.w,
                 v2.x,v2.y,v2.z,v2.w, v3.x,v3.y,v3.z,v3.w};
  float aA[8], aB[8];
  #pragma unroll
  for (int h=0;h<8;h++){ aA[h] = wa[16*8+h]; aB[h] = wa[136+16*8+h]; }
  #pragma unroll
  for (int k=0;k<16;k++){
    #pragma unroll
    for (int h=0;h<8;h++){
      aA[h] = fmaf(x[k], wa[k*8+h], aA[h]);
      aB[h] = fmaf(x[k], wa[136+k*8+h], aB[h]);
    }
  }
  float4* pa = (float4*)(sA + (long long)n*8);
  pa[0] = make_float4(aA[0],aA[1],aA[2],aA[3]); pa[1] = make_float4(aA[4],aA[5],aA[6],aA[7]);
  float4* pb = (float4*)(sB + (long long)n*8);
  pb[0] = make_float4(aB[0],aB[1],aB[2],aB[3]); pb[1] = make_float4(aB[4],aB[5],aB[6],aB[7]);
}

// ---- projection: H[n,256] = X[n,16] @ W[16,256] + b, bf16 ----
__global__ __launch_bounds__(256) void proj_kernel(const float* __restrict__ X,
    const float* __restrict__ W, const float* __restrict__ b,
    unsigned short* __restrict__ H, int N)
{
  __shared__ float Wl[16*256];
  __shared__ float bl[256];
  __shared__ float xs[8*16];
  int tid = threadIdx.x;
  #pragma unroll
  for (int i=0;i<16;i++) Wl[i*256+tid] = W[i*256+tid];
  bl[tid] = b[tid];
  int nh = tid>>7;
  int c2 = (tid&127)*2;
  for (int base = blockIdx.x*8; base < N; base += gridDim.x*8) {
    __syncthreads();
    if (tid < 128) {
      int n = tid>>4, k = tid&15;
      int node = base + n;
      xs[tid] = (node < N) ? X[(long long)node*16+k] : 0.f;
    }
    __syncthreads();
    #pragma unroll
    for (int np=0;np<4;np++){
      int n = np*2 + nh;
      int node = base+n;
      if (node < N){
        float a0 = bl[c2], a1 = bl[c2+1];
        #pragma unroll
        for (int k=0;k<16;k++){
          float xv = xs[n*16+k];
          a0 = fmaf(xv, Wl[k*256+c2],   a0);
          a1 = fmaf(xv, Wl[k*256+c2+1], a1);
        }
        *(unsigned*)&H[(long long)node*256 + c2] = (unsigned)f2b(a0) | ((unsigned)f2b(a1)<<16);
      }
    }
  }
}

// ---- fused degree histogram for both relations ----
__global__ __launch_bounds__(256) void hist2(const int* __restrict__ src, const int* __restrict__ dst,
    int* __restrict__ cnt_c, int* __restrict__ cnt_p, int E)
{
  int e = blockIdx.x*256 + threadIdx.x;
  if (e >= E) return;
  atomicAdd(&cnt_p[dst[e]], 1);
  atomicAdd(&cnt_c[src[e]], 1);
}

// ---- generic histogram over int keys ----
__global__ __launch_bounds__(256) void hist1(const int* __restrict__ key, int* __restrict__ cnt, int E)
{
  int e = blockIdx.x*256 + threadIdx.x;
  if (e < E) atomicAdd(&cnt[key[e]], 1);
}

// ---- hierarchical exclusive scan ----
__global__ __launch_bounds__(256) void scan_phase1(const int* __restrict__ cnt, int* __restrict__ bsum, int N)
{
  __shared__ int red[256];
  int tid = threadIdx.x;
  int base = blockIdx.x*1024 + tid*4;
  int s = 0;
  #pragma unroll
  for (int k=0;k<4;k++){ int i=base+k; if (i<N) s += cnt[i]; }
  red[tid] = s;
  __syncthreads();
  for (int off=128; off>0; off>>=1){ if (tid<off) red[tid]+=red[tid+off]; __syncthreads(); }
  if (tid==0) bsum[blockIdx.x] = red[0];
}

__global__ __launch_bounds__(256) void scan_phase2(int* __restrict__ bsum, int B,
    int* __restrict__ rowptr, int N)
{
  __shared__ int ts[256];
  int tid = threadIdx.x;
  int v = (tid<B) ? bsum[tid] : 0;
  ts[tid] = v;
  __syncthreads();
  for (int off=1; off<256; off<<=1){
    int t = (tid>=off) ? ts[tid-off] : 0;
    __syncthreads();
    ts[tid] += t;
    __syncthreads();
  }
  if (tid < B) bsum[tid] = ts[tid] - v;
  if (tid == B-1) rowptr[N] = ts[tid];
}

__global__ __launch_bounds__(256) void scan_phase3(const int* __restrict__ cnt,
    const int* __restrict__ bsum, int* __restrict__ rowptr, int N)
{
  __shared__ int ts[256];
  int tid = threadIdx.x;
  int base = blockIdx.x*1024 + tid*4;
  int v[4]; int s = 0;
  #pragma unroll
  for (int k=0;k<4;k++){ int i=base+k; v[k] = (i<N) ? cnt[i] : 0; s += v[k]; }
  ts[tid] = s;
  __syncthreads();
  for (int off=1; off<256; off<<=1){
    int t = (tid>=off) ? ts[tid-off] : 0;
    __syncthreads();
    ts[tid] += t;
    __syncthreads();
  }
  int run = bsum[blockIdx.x] + ts[tid] - s;
  #pragma unroll
  for (int k=0;k<4;k++){ int i=base+k; if (i<N){ rowptr[i]=run; run += v[k]; } }
}

// ---- fused placement for both relations ----
__global__ __launch_bounds__(256) void place2(const int* __restrict__ src, const int* __restrict__ dst,
    const int* __restrict__ rp_r, const int* __restrict__ rp_rb,
    int* __restrict__ cnt_p, int* __restrict__ cnt_c,
    int* __restrict__ si_r, int* __restrict__ si_rb, int E)
{
  int e = blockIdx.x*256 + threadIdx.x;
  if (e >= E) return;
  int s = src[e], d = dst[e];
  si_r [rp_r [d] + atomicAdd(&cnt_p[d], 1)] = s;
  si_rb[rp_rb[s] + atomicAdd(&cnt_c[s], 1)] = d;
}

// ---- label sort placement: perm[pos] = original batch index ----
__global__ __launch_bounds__(256) void place_label(const int* __restrict__ key,
    const int* __restrict__ rowp, int* __restrict__ cnt, int* __restrict__ perm, int B)
{
  int i = blockIdx.x*256 + threadIdx.x;
  if (i >= B) return;
  int k = key[i];
  perm[rowp[k] + atomicAdd(&cnt[k], 1)] = i;
}

// ---- aggregation: one wave per dst node; H-row gather, value loop unrolled x4 ----
__global__ __launch_bounds__(256) void agg_kernel(
    const int* __restrict__ rowptr, const int* __restrict__ srcidx,
    const float* __restrict__ sSrc, const float* __restrict__ sDst,
    const unsigned short* __restrict__ H, unsigned short* __restrict__ out, int N)
{
  int wv = threadIdx.x >> 6, lane = threadIdx.x & 63;
  int n = blockIdx.x*4 + wv;
  if (n >= N) return;
  int e0 = rowptr[n], e1 = rowptr[n+1];
  int h8 = lane & 7, j8 = lane >> 3;
  float sd8 = sDst[(long long)n*8 + h8];
  float part = 0.f;
  for (int e = e0 + j8; e < e1; e += 8){
    float l = sSrc[(long long)srcidx[e]*8 + h8] + sd8;
    float ll = l > 0.f ? l : 0.2f*l;
    part += __expf(ll);
  }
  part += __shfl_xor(part, 8);
  part += __shfl_xor(part, 16);
  part += __shfl_xor(part, 32);
  int h = lane >> 3;
  float dh  = __shfl(part, h);
  float sdh = __shfl(sd8,  h);
  float inv = 1.f/(dh + 1e-16f);
  float r0=0.f,r1=0.f,r2=0.f,r3=0.f;
  float q0=0.f,q1=0.f,q2=0.f,q3=0.f;
  float t0=0.f,t1=0.f,t2=0.f,t3=0.f;
  float u0=0.f,u1=0.f,u2=0.f,u3=0.f;
  int e = e0;
  for (; e+4 <= e1; e += 4){
    int sA = srcidx[e], sB = srcidx[e+1], sC = srcidx[e+2], sD = srcidx[e+3];
    float lA = sSrc[(long long)sA*8 + h] + sdh;
    float lB = sSrc[(long long)sB*8 + h] + sdh;
    float lC = sSrc[(long long)sC*8 + h] + sdh;
    float lD = sSrc[(long long)sD*8 + h] + sdh;
    uint2 uA = *(const uint2*)&H[(long long)sA*256 + lane*4];
    uint2 uB = *(const uint2*)&H[(long long)sB*256 + lane*4];
    uint2 uC = *(const uint2*)&H[(long long)sC*256 + lane*4];
    uint2 uD = *(const uint2*)&H[(long long)sD*256 + lane*4];
    float aA = __expf(lA > 0.f ? lA : 0.2f*lA)*inv;
    float aB = __expf(lB > 0.f ? lB : 0.2f*lB)*inv;
    float aC = __expf(lC > 0.f ? lC : 0.2f*lC)*inv;
    float aD = __expf(lD > 0.f ? lD : 0.2f*lD)*inv;
    r0 = fmaf(aA, b2f((unsigned short)(uA.x&0xffffu)), r0);
    r1 = fmaf(aA, b2f((unsigned short)(uA.x>>16)),     r1);
    r2 = fmaf(aA, b2f((unsigned short)(uA.y&0xffffu)), r2);
    r3 = fmaf(aA, b2f((unsigned short)(uA.y>>16)),     r3);
    q0 = fmaf(aB, b2f((unsigned short)(uB.x&0xffffu)), q0);
    q1 = fmaf(aB, b2f((unsigned short)(uB.x>>16)),     q1);
    q2 = fmaf(aB, b2f((unsigned short)(uB.y&0xffffu)), q2);
    q3 = fmaf(aB, b2f((unsigned short)(uB.y>>16)),     q3);
    t0 = fmaf(aC, b2f((unsigned short)(uC.x&0xffffu)), t0);
    t1 = fmaf(aC, b2f((unsigned short)(uC.x>>16)),     t1);
    t2 = fmaf(aC, b2f((unsigned short)(uC.y&0xffffu)), t2);
    t3 = fmaf(aC, b2f((unsigned short)(uC.y>>16)),     t3);
    u0 = fmaf(aD, b2f((unsigned short)(uD.x&0xffffu)), u0);
    u1 = fmaf(aD, b2f((unsigned short)(uD.x>>16)),     u1);
    u2 = fmaf(aD, b2f((unsigned short)(uD.y&0xffffu)), u2);
    u3 = fmaf(aD, b2f((unsigned short)(uD.y>>16)),     u3);
  }
  for (; e < e1; e++){
    int s = srcidx[e];
    float l = sSrc[(long long)s*8 + h] + sdh;
    float a = __expf(l > 0.f ? l : 0.2f*l)*inv;
    uint2 u = *(const uint2*)&H[(long long)s*256 + lane*4];
    r0 = fmaf(a, b2f((unsigned short)(u.x&0xffffu)), r0);
    r1 = fmaf(a, b2f((unsigned short)(u.x>>16)),     r1);
    r2 = fmaf(a, b2f((unsigned short)(u.y&0xffffu)), r2);
    r3 = fmaf(a, b2f((unsigned short)(u.y>>16)),     r3);
  }
  r0 += q0+t0+u0; r1 += q1+t1+u1; r2 += q2+t2+u2; r3 += q3+t3+u3;
  uint2 o;
  o.x = (unsigned)f2b(fmaxf(r0,0.f)) | ((unsigned)f2b(fmaxf(r1,0.f))<<16);
  o.y = (unsigned)f2b(fmaxf(r2,0.f)) | ((unsigned)f2b(fmaxf(r3,0.f))<<16);
  *(uint2*)&out[(long long)n*256 + lane*4] = o;
}

// ---- Bt prep ----
__global__ __launch_bounds__(256) void prep_bt(const float* __restrict__ fc1W, unsigned short* __restrict__ Bt)
{
  int tid = blockIdx.x*256 + threadIdx.x;
  if (tid >= 128*544) return;
  int n = tid/544, k = tid%544;
  Bt[tid] = (k < 528) ? f2b(fc1W[k*128 + n]) : (unsigned short)0;
}

// ---- T1 (MFMA): rows in label-sorted order via perm; Bt reg prefetch ----
__global__ __launch_bounds__(256) void fc1_mfma(
    const unsigned short* __restrict__ outC, const unsigned short* __restrict__ outP,
    const float* __restrict__ size_emb, const float* __restrict__ color_emb,
    const float* __restrict__ group_emb,
    const int* __restrict__ perm,
    const int* __restrict__ lsrc, const int* __restrict__ ldst,
    const int* __restrict__ sidx, const int* __restrict__ cidx, const int* __restrict__ gidx,
    const unsigned short* __restrict__ Bt, const float* __restrict__ fc1b,
    unsigned short* __restrict__ x1, float* __restrict__ bnsum)
{
  __shared__ unsigned feat_u[68*132];
  __shared__ float red[256];
  __shared__ int lsl[32], ldl[32], sil[32], cil[32], gil[32];
  int tid = threadIdx.x;
  int base = blockIdx.x*32;
  if (tid < 32){
    int g = perm[base+tid];
    lsl[tid]=lsrc[g]; ldl[tid]=ldst[g];
    sil[tid]=sidx[g]; cil[tid]=cidx[g]; gil[tid]=gidx[g];
  }
  __syncthreads();
  // graph part as uint4: 32 rows x 64 chunks (sorted lsl -> near-sequential out_c reads)
  for (int idx=tid; idx<32*64; idx+=256){
    int r = idx>>6, c = idx&63;
    uint4 u;
    if (c<32) u = ((const uint4*)&outC[(long long)lsl[r]*256])[c];
    else      u = ((const uint4*)&outP[(long long)ldl[r]*256])[c-32];
    *(uint4*)&feat_u[c*132 + r*4] = u;
  }
  // embed pairs p=256..263 + zero pad p=264..271
  for (int idx=tid; idx<32*16; idx+=256){
    int r = idx>>4, q = idx&15;
    int p = 256 + q;
    unsigned u = 0;
    if (q < 8){
      float v0, v1;
      int c0 = q*2;
      #pragma unroll
      for (int t=0;t<2;t++){
        int c = c0+t;
        float v;
        if (c<4)       v = size_emb [sil[r]*4 + c];
        else if (c<12) v = color_emb[cil[r]*8 + (c-4)];
        else           v = group_emb[gil[r]*4 + (c-12)];
        if (t==0) v0=v; else v1=v;
      }
      u = (unsigned)f2b(v0) | ((unsigned)f2b(v1)<<16);
    }
    feat_u[(p>>2)*132 + r*4 + (p&3)] = u;
  }
  __syncthreads();
  int wv = tid>>6, lane = tid&63;
  int m = lane&31, hi = lane>>5;
  f32x16 acc;
  #pragma unroll
  for (int i=0;i<16;i++) acc[i]=0.f;
  const unsigned short* btp = Bt + ((long long)(wv*32 + m))*544 + hi*8;
  bf16x8 bcur = *(const bf16x8*)(btp);
  #pragma unroll 2
  for (int ks=0; ks<34; ks++){
    bf16x8 bnext = (ks<33) ? *(const bf16x8*)(btp + (ks+1)*16) : bcur;
    bf16x8 a = *(const bf16x8*)(feat_u + (2*ks+hi)*132 + m*4);
    acc = __builtin_amdgcn_mfma_f32_32x32x16_bf16(a, bcur, acc, 0, 0, 0);
    bcur = bnext;
  }
  int col = wv*32 + (lane&31);
  float bias = fc1b[col];
  float s=0.f, q=0.f;
  #pragma unroll
  for (int reg=0; reg<16; reg++){
    int row = (reg&3) + 8*(reg>>2) + 4*hi;
    float v = fmaxf(acc[reg] + bias, 0.f);
    x1[(long long)(base+row)*128 + col] = f2b(v);
    s += v; q += v*v;
  }
  s += __shfl_xor(s, 32);
  q += __shfl_xor(q, 32);
  if (hi == 0){ red[col] = s; red[128+col] = q; }
  __syncthreads();
  if (tid < 128){
    atomicAdd(&bnsum[tid],     red[tid]);
    atomicAdd(&bnsum[128+tid], red[128+tid]);
  }
}

// ---- T2: fold BN1 into fc2 ----
__global__ void bn1_fold(const float* __restrict__ bnsum,
    const float* __restrict__ gamma, const float* __restrict__ beta,
    const float* __restrict__ fc2W, const float* __restrict__ fc2b,
    float* __restrict__ fc2p, float* __restrict__ b2p, float invB)
{
  __shared__ float sc[128], sh[128];
  int tid = threadIdx.x;
  if (tid<128){
    float mu  = bnsum[tid]*invB;
    float var = bnsum[128+tid]*invB - mu*mu;
    float s = gamma[tid] * rsqrtf(var + 1e-5f);
    sc[tid]=s; sh[tid]= beta[tid] - mu*s;
  }
  __syncthreads();
  for (int idx=tid; idx<128*32; idx+=256){ int k=idx>>5; fc2p[idx] = sc[k]*fc2W[idx]; }
  if (tid<32){
    float a = fc2b[tid];
    for (int k=0;k<128;k++) a = fmaf(sh[k], fc2W[k*32+tid], a);
    b2p[tid]=a;
  }
}

// ---- T3: x2 = relu(x1 @ fc2' + b2') bf16, BN2 stats ----
__global__ __launch_bounds__(256) void fc2_kernel(const unsigned short* __restrict__ x1,
    const float* __restrict__ fc2p, const float* __restrict__ b2p,
    unsigned short* __restrict__ x2, float* __restrict__ bnsum2)
{
  __shared__ float xt[64*128];
  __shared__ float Wl[128*32];
  __shared__ float redS[8][32];
  __shared__ float redQ[8][32];
  int tid = threadIdx.x;
  for (int idx=tid; idx<4096; idx+=256) Wl[idx]=fc2p[idx];
  long long base = (long long)blockIdx.x*64;
  const unsigned* x1u = (const unsigned*)x1;
  for (int idx=tid; idx<64*64; idx+=256){
    unsigned u = x1u[base*64 + idx];
    xt[idx*2]   = b2f((unsigned short)(u&0xffffu));
    xt[idx*2+1] = b2f((unsigned short)(u>>16));
  }
  __syncthreads();
  int tx=tid&31, ty=tid>>5;
  float acc[8];
  float bb=b2p[tx];
  #pragma unroll
  for (int i=0;i<8;i++) acc[i]=bb;
  for (int k=0;k<128;k++){
    float w=Wl[k*32+tx];
    #pragma unroll
    for (int i=0;i<8;i++) acc[i]=fmaf(xt[(ty*8+i)*128+k], w, acc[i]);
  }
  float s=0,q=0;
  #pragma unroll
  for (int i=0;i<8;i++){
    float v=fmaxf(acc[i],0.f);
    x2[(base+ty*8+i)*32+tx]=f2b(v);
    s+=v; q+=v*v;
  }
  redS[ty][tx]=s; redQ[ty][tx]=q;
  __syncthreads();
  if (tid<32){
    float a=0,b=0;
    #pragma unroll
    for (int j=0;j<8;j++){ a+=redS[j][tid]; b+=redQ[j][tid]; }
    atomicAdd(&bnsum2[tid],a); atomicAdd(&bnsum2[32+tid],b);
  }
}

// ---- T4: fold BN2 into fc3 ----
__global__ void bn2_fold(const float* __restrict__ bnsum2,
    const float* __restrict__ gamma2, const float* __restrict__ beta2,
    const float* __restrict__ fc3W, const float* __restrict__ fc3b,
    float* __restrict__ w3p, float invB)
{
  __shared__ float sh3[32];
  int tid = threadIdx.x;
  if (tid<32){
    float mu  = bnsum2[tid]*invB;
    float var = bnsum2[32+tid]*invB - mu*mu;
    float s   = gamma2[tid] * rsqrtf(var + 1e-5f);
    float shv = beta2[tid] - mu*s;
    float w   = fc3W[tid];
    w3p[tid]  = s*w;
    sh3[tid]  = shv*w;
  }
  __syncthreads();
  if (tid==0){
    float a = fc3b[0];
    for (int j=0;j<32;j++) a += sh3[j];
    w3p[32] = a;
  }
}

// ---- T5: out[perm[row]] = x2[row] @ w3' + b3' (fp32 out, un-permute) ----
__global__ __launch_bounds__(256) void fc3_kernel(const unsigned short* __restrict__ x2,
    const float* __restrict__ w3p, const int* __restrict__ perm, float* __restrict__ out)
{
  __shared__ float wl[34];
  int tid = threadIdx.x;
  if (tid<33) wl[tid]=w3p[tid];
  __syncthreads();
  long long row = (long long)blockIdx.x*32 + (tid>>3);
  int j0 = (tid&7)*4;
  uint2 u = *(const uint2*)(x2 + row*32 + j0);
  float a = b2f((unsigned short)(u.x&0xffffu))*wl[j0]
          + b2f((unsigned short)(u.x>>16))   *wl[j0+1]
          + b2f((unsigned short)(u.y&0xffffu))*wl[j0+2]
          + b2f((unsigned short)(u.y>>16))   *wl[j0+3];
  a += __shfl_xor(a,1);
  a += __shfl_xor(a,2);
  a += __shfl_xor(a,4);
  if ((tid&7)==0) out[perm[row]] = a + wl[32];
}

extern "C" void kernel_launch(void* const* d_in, const int* in_sizes, int n_in,
                              void* d_out, int out_size, void* d_ws, size_t ws_size,
                              hipStream_t stream)
{
  (void)in_sizes; (void)n_in; (void)out_size; (void)ws_size;
  const float* customer_x = (const float*)d_in[0];
  const float* product_x  = (const float*)d_in[1];
  const float* pcW = (const float*)d_in[2];
  const float* pcB = (const float*)d_in[3];
  const float* ppW = (const float*)d_in[4];
  const float* ppB = (const float*)d_in[5];
  const float* att_src_r  = (const float*)d_in[6];
  const float* att_dst_r  = (const float*)d_in[7];
  const float* att_src_rb = (const float*)d_in[8];
  const float* att_dst_rb = (const float*)d_in[9];
  // d_in[10..12] dead (semantic softmax over 1 metapath == 1)
  const float* color_emb = (const float*)d_in[13];
  const float* size_emb  = (const float*)d_in[14];
  const float* group_emb = (const float*)d_in[15];
  const float* fc1W = (const float*)d_in[16];
  const float* fc1b = (const float*)d_in[17];
  const float* fc2W = (const float*)d_in[18];
  const float* fc2b = (const float*)d_in[19];
  const float* fc3W = (const float*)d_in[20];
  const float* fc3b = (const float*)d_in[21];
  const float* bn1g = (const float*)d_in[22];
  const float* bn1b = (const float*)d_in[23];
  const float* bn2g = (const float*)d_in[24];
  const float* bn2b = (const float*)d_in[25];
  const int* edge_src  = (const int*)d_in[26];
  const int* edge_dst  = (const int*)d_in[27];
  const int* label_src = (const int*)d_in[28];
  const int* label_dst = (const int*)d_in[29];
  const int* size_idx  = (const int*)d_in[30];
  const int* color_idx = (const int*)d_in[31];
  const int* group_idx = (const int*)d_in[32];

  char* ws = (char*)d_ws;
  size_t off = 0;
  auto alloc = [&](size_t bytes)->char* {
    char* p = ws + off;
    off += (bytes + 255) & ~(size_t)255;
    return p;
  };
  // ~235 MB peak (< 256 MiB hard limit per R1/R2 fault evidence)
  unsigned short* H_c  = (unsigned short*)alloc((size_t)NCC*256*2);   // 102.4 MB; out_c aliases after agg_r
  unsigned short* H_p  = (unsigned short*)alloc((size_t)NPRR*256*2);  // 51.2 MB; x1b aliases after agg_rb
  unsigned short* out_p= (unsigned short*)alloc((size_t)NPRR*256*2);  // 51.2 MB
  float* s_cr     = (float*)alloc((size_t)NCC*8*4);     // 6.4 MB (x2b aliases after aggs)
  float* s_crb    = (float*)alloc((size_t)NCC*8*4);     // 6.4 MB
  float* s_pr     = (float*)alloc((size_t)NPRR*8*4);    // 3.2 MB
  float* s_prb    = (float*)alloc((size_t)NPRR*8*4);    // 3.2 MB
  int* rowptr_r   = (int*)alloc((size_t)(NPRR+1)*4);
  int* rowptr_rb  = (int*)alloc((size_t)(NCC+1)*4);
  int* srcidx_r   = (int*)alloc((size_t)NEE*4);         // 2 MB
  int* srcidx_rb  = (int*)alloc((size_t)NEE*4);         // 2 MB
  int* cnt_c      = (int*)alloc((size_t)NCC*4);
  int* cnt_p      = (int*)alloc((size_t)NPRR*4);
  int* lcnt       = (int*)alloc((size_t)NCC*4);         // label-sort counters
  int* lrow       = (int*)alloc((size_t)(NCC+1)*4);     // label-sort rowptr
  int* perm       = (int*)alloc((size_t)NBB*4);         // sorted-order -> original index
  int* bsum_c     = (int*)alloc(256*4);
  int* bsum_p     = (int*)alloc(256*4);
  int* bsum_l     = (int*)alloc(256*4);
  unsigned short* Bt = (unsigned short*)alloc(128*544*2);
  float* wa_c   = (float*)alloc(272*4);
  float* wa_p   = (float*)alloc(272*4);
  float* bnsum1 = (float*)alloc(256*4);
  float* bnsum2 = (float*)alloc(64*4);
  float* fc2p   = (float*)alloc(4096*4);
  float* b2p    = (float*)alloc(32*4);
  float* w3p    = (float*)alloc(34*4);
  unsigned short* out_c = H_c;                   // H_c dead after agg_r
  unsigned short* x1b   = H_p;                   // H_p dead after agg_rb
  unsigned short* x2b   = (unsigned short*)s_cr; // scores dead after aggs

  hipMemsetAsync(bnsum1, 0, 1280, stream);       // bnsum1+bnsum2 contiguous
  hipMemsetAsync(cnt_c, 0, (size_t)NCC*4, stream);
  hipMemsetAsync(cnt_p, 0, (size_t)NPRR*4, stream);
  hipMemsetAsync(lcnt,  0, (size_t)NCC*4, stream);

  // scores via algebraic fusion
  wa_prep<<<1,256,0,stream>>>(pcW, pcB, att_src_r, att_dst_rb, wa_c);
  wa_prep<<<1,256,0,stream>>>(ppW, ppB, att_dst_r, att_src_rb, wa_p);
  score_kernel<<<(NCC +255)/256,256,0,stream>>>(customer_x, wa_c, s_cr, s_crb, NCC);
  score_kernel<<<(NPRR+255)/256,256,0,stream>>>(product_x,  wa_p, s_pr, s_prb, NPRR);

  // projections -> bf16 H
  proj_kernel<<<2048,256,0,stream>>>(customer_x, pcW, pcB, H_c, NCC);
  proj_kernel<<<2048,256,0,stream>>>(product_x,  ppW, ppB, H_p, NPRR);

  // CSR build (both relations) + label sort
  const int eg = (NEE+255)/256;
  const int bg = (NBB+255)/256;
  const int BP = (NPRR+1023)/1024;   // 98
  const int BC = (NCC +1023)/1024;   // 196
  hist2<<<eg,256,0,stream>>>(edge_src, edge_dst, cnt_c, cnt_p, NEE);
  hist1<<<bg,256,0,stream>>>(label_src, lcnt, NBB);
  scan_phase1<<<BP,256,0,stream>>>(cnt_p, bsum_p, NPRR);
  scan_phase2<<<1,256,0,stream>>>(bsum_p, BP, rowptr_r, NPRR);
  scan_phase3<<<BP,256,0,stream>>>(cnt_p, bsum_p, rowptr_r, NPRR);
  scan_phase1<<<BC,256,0,stream>>>(cnt_c, bsum_c, NCC);
  scan_phase2<<<1,256,0,stream>>>(bsum_c, BC, rowptr_rb, NCC);
  scan_phase3<<<BC,256,0,stream>>>(cnt_c, bsum_c, rowptr_rb, NCC);
  scan_phase1<<<BC,256,0,stream>>>(lcnt, bsum_l, NCC);
  scan_phase2<<<1,256,0,stream>>>(bsum_l, BC, lrow, NCC);
  scan_phase3<<<BC,256,0,stream>>>(lcnt, bsum_l, lrow, NCC);
  hipMemsetAsync(cnt_c, 0, (size_t)NCC*4, stream);
  hipMemsetAsync(cnt_p, 0, (size_t)NPRR*4, stream);
  hipMemsetAsync(lcnt,  0, (size_t)NCC*4, stream);
  place2<<<eg,256,0,stream>>>(edge_src, edge_dst, rowptr_r, rowptr_rb,
      cnt_p, cnt_c, srcidx_r, srcidx_rb, NEE);
  place_label<<<bg,256,0,stream>>>(label_src, lrow, lcnt, perm, NBB);

  // gather-style aggregation (no atomics), H-row gather + x4 unroll
  agg_kernel<<<(NPRR+3)/4,256,0,stream>>>(rowptr_r,  srcidx_r,  s_cr,  s_pr,  H_c, out_p, NPRR);
  agg_kernel<<<(NCC +3)/4,256,0,stream>>>(rowptr_rb, srcidx_rb, s_prb, s_crb, H_p, out_c, NCC);

  // tail MLP in label-sorted order: MFMA fc1 + folded BN; fc3 un-permutes
  prep_bt<<<(128*544+255)/256,256,0,stream>>>(fc1W, Bt);
  fc1_mfma<<<NBB/32,256,0,stream>>>(out_c, out_p, size_emb, color_emb, group_emb,
      perm, label_src, label_dst, size_idx, color_idx, group_idx, Bt, fc1b, x1b, bnsum1);
  bn1_fold<<<1,256,0,stream>>>(bnsum1, bn1g, bn1b, fc2W, fc2b, fc2p, b2p, 1.0f/NBB);
  fc2_kernel<<<NBB/64,256,0,stream>>>(x1b, fc2p, b2p, x2b, bnsum2);
  bn2_fold<<<1,64,0,stream>>>(bnsum2, bn2g, bn2b, fc3W, fc3b, w3p, 1.0f/NBB);
  fc3_kernel<<<NBB/32,256,0,stream>>>(x2b, w3p, perm, (float*)d_out);
}

// Round 11
// 783.051 us; speedup vs baseline: 1.0793x; 1.0793x over previous
//
#include <hip/hip_runtime.h>

#define NCC 200000
#define NPRR 100000
#define NEE 500000
#define NBB 200000

typedef __attribute__((ext_vector_type(8))) short bf16x8;
typedef __attribute__((ext_vector_type(16))) float f32x16;

__device__ __forceinline__ float b2f(unsigned short u){ return __uint_as_float(((unsigned)u)<<16); }
__device__ __forceinline__ unsigned short f2b(float f){
  unsigned x = __float_as_uint(f);
  return (unsigned short)((x + 0x7fffu + ((x>>16)&1u)) >> 16);
}

// ---- WA prep ----
__global__ __launch_bounds__(256) void wa_prep(const float* __restrict__ W,
    const float* __restrict__ bias,
    const float* __restrict__ attA, const float* __restrict__ attB,
    float* __restrict__ WA)
{
  int tid = threadIdx.x;
  for (int task = tid; task < 2*17*8; task += 256) {
    int set = task / 136, rem = task % 136;
    int k = rem >> 3, h = rem & 7;
    const float* att = set ? attB : attA;
    const float* row = (k < 16) ? (W + k*256) : bias;
    float acc = 0.f;
    for (int d = 0; d < 32; d++) acc = fmaf(row[h*32+d], att[h*32+d], acc);
    WA[task] = acc;
  }
}

// ---- scores ----
__global__ __launch_bounds__(256) void score_kernel(const float* __restrict__ X,
    const float* __restrict__ WA, float* __restrict__ sA, float* __restrict__ sB, int N)
{
  __shared__ float wa[272];
  int tid = threadIdx.x;
  for (int i = tid; i < 272; i += 256) wa[i] = WA[i];
  __syncthreads();
  int n = blockIdx.x*256 + tid;
  if (n >= N) return;
  const float4* px = (const float4*)(X + (long long)n*16);
  float4 v0 = px[0], v1 = px[1], v2 = px[2], v3 = px[3];
  float x[16] = {v0.x,v0.y,v0.z,v0.w, v1.x,v1.y,v1.z,v1.w,
                 v2.x,v2.y,v2.z,v2.w, v3.x,v3.y,v3.z,v3.w};
  float aA[8], aB[8];
  #pragma unroll
  for (int h=0;h<8;h++){ aA[h] = wa[16*8+h]; aB[h] = wa[136+16*8+h]; }
  #pragma unroll
  for (int k=0;k<16;k++){
    #pragma unroll
    for (int h=0;h<8;h++){
      aA[h] = fmaf(x[k], wa[k*8+h], aA[h]);
      aB[h] = fmaf(x[k], wa[136+k*8+h], aB[h]);
    }
  }
  float4* pa = (float4*)(sA + (long long)n*8);
  pa[0] = make_float4(aA[0],aA[1],aA[2],aA[3]); pa[1] = make_float4(aA[4],aA[5],aA[6],aA[7]);
  float4* pb = (float4*)(sB + (long long)n*8);
  pb[0] = make_float4(aB[0],aB[1],aB[2],aB[3]); pb[1] = make_float4(aB[4],aB[5],aB[6],aB[7]);
}

// ---- projection: H[n,256] = X[n,16] @ W[16,256] + b, bf16 ----
__global__ __launch_bounds__(256) void proj_kernel(const float* __restrict__ X,
    const float* __restrict__ W, const float* __restrict__ b,
    unsigned short* __restrict__ H, int N)
{
  __shared__ float Wl[16*256];
  __shared__ float bl[256];
  __shared__ float xs[8*16];
  int tid = threadIdx.x;
  #pragma unroll
  for (int i=0;i<16;i++) Wl[i*256+tid] = W[i*256+tid];
  bl[tid] = b[tid];
  int nh = tid>>7;
  int c2 = (tid&127)*2;
  for (int base = blockIdx.x*8; base < N; base += gridDim.x*8) {
    __syncthreads();
    if (tid < 128) {
      int n = tid>>4, k = tid&15;
      int node = base + n;
      xs[tid] = (node < N) ? X[(long long)node*16+k] : 0.f;
    }
    __syncthreads();
    #pragma unroll
    for (int np=0;np<4;np++){
      int n = np*2 + nh;
      int node = base+n;
      if (node < N){
        float a0 = bl[c2], a1 = bl[c2+1];
        #pragma unroll
        for (int k=0;k<16;k++){
          float xv = xs[n*16+k];
          a0 = fmaf(xv, Wl[k*256+c2],   a0);
          a1 = fmaf(xv, Wl[k*256+c2+1], a1);
        }
        *(unsigned*)&H[(long long)node*256 + c2] = (unsigned)f2b(a0) | ((unsigned)f2b(a1)<<16);
      }
    }
  }
}

// ---- fused degree histogram for both relations ----
__global__ __launch_bounds__(256) void hist2(const int* __restrict__ src, const int* __restrict__ dst,
    int* __restrict__ cnt_c, int* __restrict__ cnt_p, int E)
{
  int e = blockIdx.x*256 + threadIdx.x;
  if (e >= E) return;
  atomicAdd(&cnt_p[dst[e]], 1);
  atomicAdd(&cnt_c[src[e]], 1);
}

// ---- hierarchical exclusive scan ----
__global__ __launch_bounds__(256) void scan_phase1(const int* __restrict__ cnt, int* __restrict__ bsum, int N)
{
  __shared__ int red[256];
  int tid = threadIdx.x;
  int base = blockIdx.x*1024 + tid*4;
  int s = 0;
  #pragma unroll
  for (int k=0;k<4;k++){ int i=base+k; if (i<N) s += cnt[i]; }
  red[tid] = s;
  __syncthreads();
  for (int off=128; off>0; off>>=1){ if (tid<off) red[tid]+=red[tid+off]; __syncthreads(); }
  if (tid==0) bsum[blockIdx.x] = red[0];
}

__global__ __launch_bounds__(256) void scan_phase2(int* __restrict__ bsum, int B,
    int* __restrict__ rowptr, int N)
{
  __shared__ int ts[256];
  int tid = threadIdx.x;
  int v = (tid<B) ? bsum[tid] : 0;
  ts[tid] = v;
  __syncthreads();
  for (int off=1; off<256; off<<=1){
    int t = (tid>=off) ? ts[tid-off] : 0;
    __syncthreads();
    ts[tid] += t;
    __syncthreads();
  }
  if (tid < B) bsum[tid] = ts[tid] - v;
  if (tid == B-1) rowptr[N] = ts[tid];
}

__global__ __launch_bounds__(256) void scan_phase3(const int* __restrict__ cnt,
    const int* __restrict__ bsum, int* __restrict__ rowptr, int N)
{
  __shared__ int ts[256];
  int tid = threadIdx.x;
  int base = blockIdx.x*1024 + tid*4;
  int v[4]; int s = 0;
  #pragma unroll
  for (int k=0;k<4;k++){ int i=base+k; v[k] = (i<N) ? cnt[i] : 0; s += v[k]; }
  ts[tid] = s;
  __syncthreads();
  for (int off=1; off<256; off<<=1){
    int t = (tid>=off) ? ts[tid-off] : 0;
    __syncthreads();
    ts[tid] += t;
    __syncthreads();
  }
  int run = bsum[blockIdx.x] + ts[tid] - s;
  #pragma unroll
  for (int k=0;k<4;k++){ int i=base+k; if (i<N){ rowptr[i]=run; run += v[k]; } }
}

// ---- fused placement for both relations (uses pre-zeroed cnt2 buffers) ----
__global__ __launch_bounds__(256) void place2(const int* __restrict__ src, const int* __restrict__ dst,
    const int* __restrict__ rp_r, const int* __restrict__ rp_rb,
    int* __restrict__ cnt_p, int* __restrict__ cnt_c,
    int* __restrict__ si_r, int* __restrict__ si_rb, int E)
{
  int e = blockIdx.x*256 + threadIdx.x;
  if (e >= E) return;
  int s = src[e], d = dst[e];
  si_r [rp_r [d] + atomicAdd(&cnt_p[d], 1)] = s;
  si_rb[rp_rb[s] + atomicAdd(&cnt_c[s], 1)] = d;
}

// ---- aggregation: SINGLE PASS — num and denom accumulated together, x4 unroll ----
__global__ __launch_bounds__(256) void agg_kernel(
    const int* __restrict__ rowptr, const int* __restrict__ srcidx,
    const float* __restrict__ sSrc, const float* __restrict__ sDst,
    const unsigned short* __restrict__ H, unsigned short* __restrict__ out, int N)
{
  int wv = threadIdx.x >> 6, lane = threadIdx.x & 63;
  int n = blockIdx.x*4 + wv;
  if (n >= N) return;
  int e0 = rowptr[n], e1 = rowptr[n+1];
  int h = lane >> 3;                      // head of this lane's 4 columns
  float sdh = sDst[(long long)n*8 + h];
  float r0=0.f,r1=0.f,r2=0.f,r3=0.f, dA=0.f;
  float q0=0.f,q1=0.f,q2=0.f,q3=0.f, dB=0.f;
  float t0=0.f,t1=0.f,t2=0.f,t3=0.f, dC=0.f;
  float u0=0.f,u1=0.f,u2=0.f,u3=0.f, dD=0.f;
  int e = e0;
  for (; e+4 <= e1; e += 4){
    int sA = srcidx[e], sB = srcidx[e+1], sC = srcidx[e+2], sD = srcidx[e+3];
    float lA = sSrc[(long long)sA*8 + h] + sdh;
    float lB = sSrc[(long long)sB*8 + h] + sdh;
    float lC = sSrc[(long long)sC*8 + h] + sdh;
    float lD = sSrc[(long long)sD*8 + h] + sdh;
    uint2 uA = *(const uint2*)&H[(long long)sA*256 + lane*4];
    uint2 uB = *(const uint2*)&H[(long long)sB*256 + lane*4];
    uint2 uC = *(const uint2*)&H[(long long)sC*256 + lane*4];
    uint2 uD = *(const uint2*)&H[(long long)sD*256 + lane*4];
    float wA = __expf(lA > 0.f ? lA : 0.2f*lA);
    float wB = __expf(lB > 0.f ? lB : 0.2f*lB);
    float wC = __expf(lC > 0.f ? lC : 0.2f*lC);
    float wD = __expf(lD > 0.f ? lD : 0.2f*lD);
    dA += wA; dB += wB; dC += wC; dD += wD;
    r0 = fmaf(wA, b2f((unsigned short)(uA.x&0xffffu)), r0);
    r1 = fmaf(wA, b2f((unsigned short)(uA.x>>16)),     r1);
    r2 = fmaf(wA, b2f((unsigned short)(uA.y&0xffffu)), r2);
    r3 = fmaf(wA, b2f((unsigned short)(uA.y>>16)),     r3);
    q0 = fmaf(wB, b2f((unsigned short)(uB.x&0xffffu)), q0);
    q1 = fmaf(wB, b2f((unsigned short)(uB.x>>16)),     q1);
    q2 = fmaf(wB, b2f((unsigned short)(uB.y&0xffffu)), q2);
    q3 = fmaf(wB, b2f((unsigned short)(uB.y>>16)),     q3);
    t0 = fmaf(wC, b2f((unsigned short)(uC.x&0xffffu)), t0);
    t1 = fmaf(wC, b2f((unsigned short)(uC.x>>16)),     t1);
    t2 = fmaf(wC, b2f((unsigned short)(uC.y&0xffffu)), t2);
    t3 = fmaf(wC, b2f((unsigned short)(uC.y>>16)),     t3);
    u0 = fmaf(wD, b2f((unsigned short)(uD.x&0xffffu)), u0);
    u1 = fmaf(wD, b2f((unsigned short)(uD.x>>16)),     u1);
    u2 = fmaf(wD, b2f((unsigned short)(uD.y&0xffffu)), u2);
    u3 = fmaf(wD, b2f((unsigned short)(uD.y>>16)),     u3);
  }
  for (; e < e1; e++){
    int s = srcidx[e];
    float l = sSrc[(long long)s*8 + h] + sdh;
    float w = __expf(l > 0.f ? l : 0.2f*l);
    uint2 u = *(const uint2*)&H[(long long)s*256 + lane*4];
    dA += w;
    r0 = fmaf(w, b2f((unsigned short)(u.x&0xffffu)), r0);
    r1 = fmaf(w, b2f((unsigned short)(u.x>>16)),     r1);
    r2 = fmaf(w, b2f((unsigned short)(u.y&0xffffu)), r2);
    r3 = fmaf(w, b2f((unsigned short)(u.y>>16)),     r3);
  }
  float inv = 1.f/((dA+dB)+(dC+dD) + 1e-16f);
  r0 = (r0+q0+t0+u0)*inv; r1 = (r1+q1+t1+u1)*inv;
  r2 = (r2+q2+t2+u2)*inv; r3 = (r3+q3+t3+u3)*inv;
  uint2 o;
  o.x = (unsigned)f2b(fmaxf(r0,0.f)) | ((unsigned)f2b(fmaxf(r1,0.f))<<16);
  o.y = (unsigned)f2b(fmaxf(r2,0.f)) | ((unsigned)f2b(fmaxf(r3,0.f))<<16);
  *(uint2*)&out[(long long)n*256 + lane*4] = o;
}

// ---- Bt prep ----
__global__ __launch_bounds__(256) void prep_bt(const float* __restrict__ fc1W, unsigned short* __restrict__ Bt)
{
  int tid = blockIdx.x*256 + threadIdx.x;
  if (tid >= 128*544) return;
  int n = tid/544, k = tid%544;
  Bt[tid] = (k < 528) ? f2b(fc1W[k*128 + n]) : (unsigned short)0;
}

// ---- T1 (MFMA): 32 rows x 128 cols; uint4 staging; Bt reg prefetch ----
__global__ __launch_bounds__(256) void fc1_mfma(
    const unsigned short* __restrict__ outC, const unsigned short* __restrict__ outP,
    const float* __restrict__ size_emb, const float* __restrict__ color_emb,
    const float* __restrict__ group_emb,
    const int* __restrict__ lsrc, const int* __restrict__ ldst,
    const int* __restrict__ sidx, const int* __restrict__ cidx, const int* __restrict__ gidx,
    const unsigned short* __restrict__ Bt, const float* __restrict__ fc1b,
    unsigned short* __restrict__ x1, float* __restrict__ bnsum)
{
  __shared__ unsigned feat_u[68*132];
  __shared__ float red[256];
  __shared__ int lsl[32], ldl[32], sil[32], cil[32], gil[32];
  int tid = threadIdx.x;
  int base = blockIdx.x*32;
  if (tid < 32){ lsl[tid]=lsrc[base+tid]; ldl[tid]=ldst[base+tid]; }
  else if (tid < 64){ int r=tid-32; sil[r]=sidx[base+r]; cil[r]=cidx[base+r]; gil[r]=gidx[base+r]; }
  __syncthreads();
  for (int idx=tid; idx<32*64; idx+=256){
    int r = idx>>6, c = idx&63;
    uint4 u;
    if (c<32) u = ((const uint4*)&outC[(long long)lsl[r]*256])[c];
    else      u = ((const uint4*)&outP[(long long)ldl[r]*256])[c-32];
    *(uint4*)&feat_u[c*132 + r*4] = u;
  }
  for (int idx=tid; idx<32*16; idx+=256){
    int r = idx>>4, q = idx&15;
    int p = 256 + q;
    unsigned u = 0;
    if (q < 8){
      float v0, v1;
      int c0 = q*2;
      #pragma unroll
      for (int t=0;t<2;t++){
        int c = c0+t;
        float v;
        if (c<4)       v = size_emb [sil[r]*4 + c];
        else if (c<12) v = color_emb[cil[r]*8 + (c-4)];
        else           v = group_emb[gil[r]*4 + (c-12)];
        if (t==0) v0=v; else v1=v;
      }
      u = (unsigned)f2b(v0) | ((unsigned)f2b(v1)<<16);
    }
    feat_u[(p>>2)*132 + r*4 + (p&3)] = u;
  }
  __syncthreads();
  int wv = tid>>6, lane = tid&63;
  int m = lane&31, hi = lane>>5;
  f32x16 acc;
  #pragma unroll
  for (int i=0;i<16;i++) acc[i]=0.f;
  const unsigned short* btp = Bt + ((long long)(wv*32 + m))*544 + hi*8;
  bf16x8 bcur = *(const bf16x8*)(btp);
  #pragma unroll 2
  for (int ks=0; ks<34; ks++){
    bf16x8 bnext = (ks<33) ? *(const bf16x8*)(btp + (ks+1)*16) : bcur;
    bf16x8 a = *(const bf16x8*)(feat_u + (2*ks+hi)*132 + m*4);
    acc = __builtin_amdgcn_mfma_f32_32x32x16_bf16(a, bcur, acc, 0, 0, 0);
    bcur = bnext;
  }
  int col = wv*32 + (lane&31);
  float bias = fc1b[col];
  float s=0.f, q=0.f;
  #pragma unroll
  for (int reg=0; reg<16; reg++){
    int row = (reg&3) + 8*(reg>>2) + 4*hi;
    float v = fmaxf(acc[reg] + bias, 0.f);
    x1[(long long)(base+row)*128 + col] = f2b(v);
    s += v; q += v*v;
  }
  s += __shfl_xor(s, 32);
  q += __shfl_xor(q, 32);
  if (hi == 0){ red[col] = s; red[128+col] = q; }
  __syncthreads();
  if (tid < 128){
    atomicAdd(&bnsum[tid],     red[tid]);
    atomicAdd(&bnsum[128+tid], red[128+tid]);
  }
}

// ---- T2: fold BN1 into fc2 ----
__global__ void bn1_fold(const float* __restrict__ bnsum,
    const float* __restrict__ gamma, const float* __restrict__ beta,
    const float* __restrict__ fc2W, const float* __restrict__ fc2b,
    float* __restrict__ fc2p, float* __restrict__ b2p, float invB)
{
  __shared__ float sc[128], sh[128];
  int tid = threadIdx.x;
  if (tid<128){
    float mu  = bnsum[tid]*invB;
    float var = bnsum[128+tid]*invB - mu*mu;
    float s = gamma[tid] * rsqrtf(var + 1e-5f);
    sc[tid]=s; sh[tid]= beta[tid] - mu*s;
  }
  __syncthreads();
  for (int idx=tid; idx<128*32; idx+=256){ int k=idx>>5; fc2p[idx] = sc[k]*fc2W[idx]; }
  if (tid<32){
    float a = fc2b[tid];
    for (int k=0;k<128;k++) a = fmaf(sh[k], fc2W[k*32+tid], a);
    b2p[tid]=a;
  }
}

// ---- T3: x2 = relu(x1 @ fc2' + b2') bf16, BN2 stats ----
__global__ __launch_bounds__(256) void fc2_kernel(const unsigned short* __restrict__ x1,
    const float* __restrict__ fc2p, const float* __restrict__ b2p,
    unsigned short* __restrict__ x2, float* __restrict__ bnsum2)
{
  __shared__ float xt[64*128];
  __shared__ float Wl[128*32];
  __shared__ float redS[8][32];
  __shared__ float redQ[8][32];
  int tid = threadIdx.x;
  for (int idx=tid; idx<4096; idx+=256) Wl[idx]=fc2p[idx];
  long long base = (long long)blockIdx.x*64;
  const unsigned* x1u = (const unsigned*)x1;
  for (int idx=tid; idx<64*64; idx+=256){
    unsigned u = x1u[base*64 + idx];
    xt[idx*2]   = b2f((unsigned short)(u&0xffffu));
    xt[idx*2+1] = b2f((unsigned short)(u>>16));
  }
  __syncthreads();
  int tx=tid&31, ty=tid>>5;
  float acc[8];
  float bb=b2p[tx];
  #pragma unroll
  for (int i=0;i<8;i++) acc[i]=bb;
  for (int k=0;k<128;k++){
    float w=Wl[k*32+tx];
    #pragma unroll
    for (int i=0;i<8;i++) acc[i]=fmaf(xt[(ty*8+i)*128+k], w, acc[i]);
  }
  float s=0,q=0;
  #pragma unroll
  for (int i=0;i<8;i++){
    float v=fmaxf(acc[i],0.f);
    x2[(base+ty*8+i)*32+tx]=f2b(v);
    s+=v; q+=v*v;
  }
  redS[ty][tx]=s; redQ[ty][tx]=q;
  __syncthreads();
  if (tid<32){
    float a=0,b=0;
    #pragma unroll
    for (int j=0;j<8;j++){ a+=redS[j][tid]; b+=redQ[j][tid]; }
    atomicAdd(&bnsum2[tid],a); atomicAdd(&bnsum2[32+tid],b);
  }
}

// ---- T4: fold BN2 into fc3 ----
__global__ void bn2_fold(const float* __restrict__ bnsum2,
    const float* __restrict__ gamma2, const float* __restrict__ beta2,
    const float* __restrict__ fc3W, const float* __restrict__ fc3b,
    float* __restrict__ w3p, float invB)
{
  __shared__ float sh3[32];
  int tid = threadIdx.x;
  if (tid<32){
    float mu  = bnsum2[tid]*invB;
    float var = bnsum2[32+tid]*invB - mu*mu;
    float s   = gamma2[tid] * rsqrtf(var + 1e-5f);
    float shv = beta2[tid] - mu*s;
    float w   = fc3W[tid];
    w3p[tid]  = s*w;
    sh3[tid]  = shv*w;
  }
  __syncthreads();
  if (tid==0){
    float a = fc3b[0];
    for (int j=0;j<32;j++) a += sh3[j];
    w3p[32] = a;
  }
}

// ---- T5: out = x2 @ w3' + b3' (fp32 out) ----
__global__ __launch_bounds__(256) void fc3_kernel(const unsigned short* __restrict__ x2,
    const float* __restrict__ w3p, float* __restrict__ out)
{
  __shared__ float wl[34];
  int tid = threadIdx.x;
  if (tid<33) wl[tid]=w3p[tid];
  __syncthreads();
  long long row = (long long)blockIdx.x*32 + (tid>>3);
  int j0 = (tid&7)*4;
  uint2 u = *(const uint2*)(x2 + row*32 + j0);
  float a = b2f((unsigned short)(u.x&0xffffu))*wl[j0]
          + b2f((unsigned short)(u.x>>16))   *wl[j0+1]
          + b2f((unsigned short)(u.y&0xffffu))*wl[j0+2]
          + b2f((unsigned short)(u.y>>16))   *wl[j0+3];
  a += __shfl_xor(a,1);
  a += __shfl_xor(a,2);
  a += __shfl_xor(a,4);
  if ((tid&7)==0) out[row] = a + wl[32];
}

extern "C" void kernel_launch(void* const* d_in, const int* in_sizes, int n_in,
                              void* d_out, int out_size, void* d_ws, size_t ws_size,
                              hipStream_t stream)
{
  (void)in_sizes; (void)n_in; (void)out_size; (void)ws_size;
  const float* customer_x = (const float*)d_in[0];
  const float* product_x  = (const float*)d_in[1];
  const float* pcW = (const float*)d_in[2];
  const float* pcB = (const float*)d_in[3];
  const float* ppW = (const float*)d_in[4];
  const float* ppB = (const float*)d_in[5];
  const float* att_src_r  = (const float*)d_in[6];
  const float* att_dst_r  = (const float*)d_in[7];
  const float* att_src_rb = (const float*)d_in[8];
  const float* att_dst_rb = (const float*)d_in[9];
  // d_in[10..12] dead (semantic softmax over 1 metapath == 1)
  const float* color_emb = (const float*)d_in[13];
  const float* size_emb  = (const float*)d_in[14];
  const float* group_emb = (const float*)d_in[15];
  const float* fc1W = (const float*)d_in[16];
  const float* fc1b = (const float*)d_in[17];
  const float* fc2W = (const float*)d_in[18];
  const float* fc2b = (const float*)d_in[19];
  const float* fc3W = (const float*)d_in[20];
  const float* fc3b = (const float*)d_in[21];
  const float* bn1g = (const float*)d_in[22];
  const float* bn1b = (const float*)d_in[23];
  const float* bn2g = (const float*)d_in[24];
  const float* bn2b = (const float*)d_in[25];
  const int* edge_src  = (const int*)d_in[26];
  const int* edge_dst  = (const int*)d_in[27];
  const int* label_src = (const int*)d_in[28];
  const int* label_dst = (const int*)d_in[29];
  const int* size_idx  = (const int*)d_in[30];
  const int* color_idx = (const int*)d_in[31];
  const int* group_idx = (const int*)d_in[32];

  char* ws = (char*)d_ws;
  size_t off = 0;
  auto alloc = [&](size_t bytes)->char* {
    char* p = ws + off;
    off += (bytes + 255) & ~(size_t)255;
    return p;
  };
  // ~234 MB peak (< 256 MiB hard limit per R1/R2 fault evidence)
  unsigned short* H_c  = (unsigned short*)alloc((size_t)NCC*256*2);   // 102.4 MB; out_c aliases after agg_r
  unsigned short* H_p  = (unsigned short*)alloc((size_t)NPRR*256*2);  // 51.2 MB; x1b aliases after agg_rb
  unsigned short* out_p= (unsigned short*)alloc((size_t)NPRR*256*2);  // 51.2 MB
  float* s_cr     = (float*)alloc((size_t)NCC*8*4);     // 6.4 MB (x2b aliases after aggs)
  float* s_crb    = (float*)alloc((size_t)NCC*8*4);     // 6.4 MB
  float* s_pr     = (float*)alloc((size_t)NPRR*8*4);    // 3.2 MB
  float* s_prb    = (float*)alloc((size_t)NPRR*8*4);    // 3.2 MB
  int* rowptr_r   = (int*)alloc((size_t)(NPRR+1)*4);
  int* rowptr_rb  = (int*)alloc((size_t)(NCC+1)*4);
  int* srcidx_r   = (int*)alloc((size_t)NEE*4);         // 2 MB
  int* srcidx_rb  = (int*)alloc((size_t)NEE*4);         // 2 MB
  // R10 crash fix: all 4 counter buffers in ONE allocation — truly contiguous,
  // memset length exact (alloc() pads each call to 256B; NPRR*4 is not 256-aligned,
  // which left cnt_p2's tail poisoned 0xAA -> place2 wrote OOB)
  int* cnts       = (int*)alloc((size_t)(NCC+NPRR)*2*4);
  int* cnt_c      = cnts;
  int* cnt_p      = cnts + NCC;
  int* cnt_c2     = cnts + NCC + NPRR;
  int* cnt_p2     = cnts + NCC + NPRR + NCC;
  int* bsum_c     = (int*)alloc(256*4);
  int* bsum_p     = (int*)alloc(256*4);
  unsigned short* Bt = (unsigned short*)alloc(128*544*2);
  float* wa_c   = (float*)alloc(272*4);
  float* wa_p   = (float*)alloc(272*4);
  float* bnsum1 = (float*)alloc(256*4);
  float* bnsum2 = (float*)alloc(64*4);
  float* fc2p   = (float*)alloc(4096*4);
  float* b2p    = (float*)alloc(32*4);
  float* w3p    = (float*)alloc(34*4);
  unsigned short* out_c = H_c;                   // H_c dead after agg_r
  unsigned short* x1b   = H_p;                   // H_p dead after agg_rb
  unsigned short* x2b   = (unsigned short*)s_cr; // scores dead after aggs

  hipMemsetAsync(bnsum1, 0, 1280, stream);       // bnsum1+bnsum2 contiguous
  hipMemsetAsync(cnts, 0, (size_t)(NCC+NPRR)*2*4, stream);  // exact: single contiguous block

  // scores via algebraic fusion
  wa_prep<<<1,256,0,stream>>>(pcW, pcB, att_src_r, att_dst_rb, wa_c);
  wa_prep<<<1,256,0,stream>>>(ppW, ppB, att_dst_r, att_src_rb, wa_p);
  score_kernel<<<(NCC +255)/256,256,0,stream>>>(customer_x, wa_c, s_cr, s_crb, NCC);
  score_kernel<<<(NPRR+255)/256,256,0,stream>>>(product_x,  wa_p, s_pr, s_prb, NPRR);

  // projections -> bf16 H
  proj_kernel<<<2048,256,0,stream>>>(customer_x, pcW, pcB, H_c, NCC);
  proj_kernel<<<2048,256,0,stream>>>(product_x,  ppW, ppB, H_p, NPRR);

  // CSR build (both relations)
  const int eg = (NEE+255)/256;
  const int BP = (NPRR+1023)/1024;   // 98
  const int BC = (NCC +1023)/1024;   // 196
  hist2<<<eg,256,0,stream>>>(edge_src, edge_dst, cnt_c, cnt_p, NEE);
  scan_phase1<<<BP,256,0,stream>>>(cnt_p, bsum_p, NPRR);
  scan_phase2<<<1,256,0,stream>>>(bsum_p, BP, rowptr_r, NPRR);
  scan_phase3<<<BP,256,0,stream>>>(cnt_p, bsum_p, rowptr_r, NPRR);
  scan_phase1<<<BC,256,0,stream>>>(cnt_c, bsum_c, NCC);
  scan_phase2<<<1,256,0,stream>>>(bsum_c, BC, rowptr_rb, NCC);
  scan_phase3<<<BC,256,0,stream>>>(cnt_c, bsum_c, rowptr_rb, NCC);
  place2<<<eg,256,0,stream>>>(edge_src, edge_dst, rowptr_r, rowptr_rb,
      cnt_p2, cnt_c2, srcidx_r, srcidx_rb, NEE);

  // single-pass gather aggregation (no atomics)
  agg_kernel<<<(NPRR+3)/4,256,0,stream>>>(rowptr_r,  srcidx_r,  s_cr,  s_pr,  H_c, out_p, NPRR);
  agg_kernel<<<(NCC +3)/4,256,0,stream>>>(rowptr_rb, srcidx_rb, s_prb, s_crb, H_p, out_c, NCC);

  // tail MLP: MFMA fc1 + folded BN
  prep_bt<<<(128*544+255)/256,256,0,stream>>>(fc1W, Bt);
  fc1_mfma<<<NBB/32,256,0,stream>>>(out_c, out_p, size_emb, color_emb, group_emb,
      label_src, label_dst, size_idx, color_idx, group_idx, Bt, fc1b, x1b, bnsum1);
  bn1_fold<<<1,256,0,stream>>>(bnsum1, bn1g, bn1b, fc2W, fc2b, fc2p, b2p, 1.0f/NBB);
  fc2_kernel<<<NBB/64,256,0,stream>>>(x1b, fc2p, b2p, x2b, bnsum2);
  bn2_fold<<<1,64,0,stream>>>(bnsum2, bn2g, bn2b, fc3W, fc3b, w3p, 1.0f/NBB);
  fc3_kernel<<<NBB/32,256,0,stream>>>(x2b, w3p, (float*)d_out);
}

// Round 12
// 777.745 us; speedup vs baseline: 1.0866x; 1.0068x over previous
//
#include <hip/hip_runtime.h>

#define NCC 200000
#define NPRR 100000
#define NEE 500000
#define NBB 200000

typedef __attribute__((ext_vector_type(8))) short bf16x8;
typedef __attribute__((ext_vector_type(16))) float f32x16;

__device__ __forceinline__ float b2f(unsigned short u){ return __uint_as_float(((unsigned)u)<<16); }
__device__ __forceinline__ unsigned short f2b(float f){
  unsigned x = __float_as_uint(f);
  return (unsigned short)((x + 0x7fffu + ((x>>16)&1u)) >> 16);
}
// async global->LDS DMA, 16B/lane; LDS dest = uniform base + lane*16 (HW)
__device__ __forceinline__ void gl2lds16(const void* g, void* l){
  __builtin_amdgcn_global_load_lds(
      (const __attribute__((address_space(1))) unsigned int*)g,
      (__attribute__((address_space(3))) unsigned int*)l, 16, 0, 0);
}

// ---- WA prep ----
__global__ __launch_bounds__(256) void wa_prep(const float* __restrict__ W,
    const float* __restrict__ bias,
    const float* __restrict__ attA, const float* __restrict__ attB,
    float* __restrict__ WA)
{
  int tid = threadIdx.x;
  for (int task = tid; task < 2*17*8; task += 256) {
    int set = task / 136, rem = task % 136;
    int k = rem >> 3, h = rem & 7;
    const float* att = set ? attB : attA;
    const float* row = (k < 16) ? (W + k*256) : bias;
    float acc = 0.f;
    for (int d = 0; d < 32; d++) acc = fmaf(row[h*32+d], att[h*32+d], acc);
    WA[task] = acc;
  }
}

// ---- scores ----
__global__ __launch_bounds__(256) void score_kernel(const float* __restrict__ X,
    const float* __restrict__ WA, float* __restrict__ sA, float* __restrict__ sB, int N)
{
  __shared__ float wa[272];
  int tid = threadIdx.x;
  for (int i = tid; i < 272; i += 256) wa[i] = WA[i];
  __syncthreads();
  int n = blockIdx.x*256 + tid;
  if (n >= N) return;
  const float4* px = (const float4*)(X + (long long)n*16);
  float4 v0 = px[0], v1 = px[1], v2 = px[2], v3 = px[3];
  float x[16] = {v0.x,v0.y,v0.z,v0.w, v1.x,v1.y,v1.z,v1.w,
                 v2.x,v2.y,v2.z,v2.w, v3.x,v3.y,v3.z,v3.w};
  float aA[8], aB[8];
  #pragma unroll
  for (int h=0;h<8;h++){ aA[h] = wa[16*8+h]; aB[h] = wa[136+16*8+h]; }
  #pragma unroll
  for (int k=0;k<16;k++){
    #pragma unroll
    for (int h=0;h<8;h++){
      aA[h] = fmaf(x[k], wa[k*8+h], aA[h]);
      aB[h] = fmaf(x[k], wa[136+k*8+h], aB[h]);
    }
  }
  float4* pa = (float4*)(sA + (long long)n*8);
  pa[0] = make_float4(aA[0],aA[1],aA[2],aA[3]); pa[1] = make_float4(aA[4],aA[5],aA[6],aA[7]);
  float4* pb = (float4*)(sB + (long long)n*8);
  pb[0] = make_float4(aB[0],aB[1],aB[2],aB[3]); pb[1] = make_float4(aB[4],aB[5],aB[6],aB[7]);
}

// ---- projection: H[n,256] = X[n,16] @ W[16,256] + b, bf16 ----
__global__ __launch_bounds__(256) void proj_kernel(const float* __restrict__ X,
    const float* __restrict__ W, const float* __restrict__ b,
    unsigned short* __restrict__ H, int N)
{
  __shared__ float Wl[16*256];
  __shared__ float bl[256];
  __shared__ float xs[8*16];
  int tid = threadIdx.x;
  #pragma unroll
  for (int i=0;i<16;i++) Wl[i*256+tid] = W[i*256+tid];
  bl[tid] = b[tid];
  int nh = tid>>7;
  int c2 = (tid&127)*2;
  for (int base = blockIdx.x*8; base < N; base += gridDim.x*8) {
    __syncthreads();
    if (tid < 128) {
      int n = tid>>4, k = tid&15;
      int node = base + n;
      xs[tid] = (node < N) ? X[(long long)node*16+k] : 0.f;
    }
    __syncthreads();
    #pragma unroll
    for (int np=0;np<4;np++){
      int n = np*2 + nh;
      int node = base+n;
      if (node < N){
        float a0 = bl[c2], a1 = bl[c2+1];
        #pragma unroll
        for (int k=0;k<16;k++){
          float xv = xs[n*16+k];
          a0 = fmaf(xv, Wl[k*256+c2],   a0);
          a1 = fmaf(xv, Wl[k*256+c2+1], a1);
        }
        *(unsigned*)&H[(long long)node*256 + c2] = (unsigned)f2b(a0) | ((unsigned)f2b(a1)<<16);
      }
    }
  }
}

// ---- fused degree histogram for both relations ----
__global__ __launch_bounds__(256) void hist2(const int* __restrict__ src, const int* __restrict__ dst,
    int* __restrict__ cnt_c, int* __restrict__ cnt_p, int E)
{
  int e = blockIdx.x*256 + threadIdx.x;
  if (e >= E) return;
  atomicAdd(&cnt_p[dst[e]], 1);
  atomicAdd(&cnt_c[src[e]], 1);
}

// ---- hierarchical exclusive scan ----
__global__ __launch_bounds__(256) void scan_phase1(const int* __restrict__ cnt, int* __restrict__ bsum, int N)
{
  __shared__ int red[256];
  int tid = threadIdx.x;
  int base = blockIdx.x*1024 + tid*4;
  int s = 0;
  #pragma unroll
  for (int k=0;k<4;k++){ int i=base+k; if (i<N) s += cnt[i]; }
  red[tid] = s;
  __syncthreads();
  for (int off=128; off>0; off>>=1){ if (tid<off) red[tid]+=red[tid+off]; __syncthreads(); }
  if (tid==0) bsum[blockIdx.x] = red[0];
}

__global__ __launch_bounds__(256) void scan_phase2(int* __restrict__ bsum, int B,
    int* __restrict__ rowptr, int N)
{
  __shared__ int ts[256];
  int tid = threadIdx.x;
  int v = (tid<B) ? bsum[tid] : 0;
  ts[tid] = v;
  __syncthreads();
  for (int off=1; off<256; off<<=1){
    int t = (tid>=off) ? ts[tid-off] : 0;
    __syncthreads();
    ts[tid] += t;
    __syncthreads();
  }
  if (tid < B) bsum[tid] = ts[tid] - v;
  if (tid == B-1) rowptr[N] = ts[tid];
}

__global__ __launch_bounds__(256) void scan_phase3(const int* __restrict__ cnt,
    const int* __restrict__ bsum, int* __restrict__ rowptr, int N)
{
  __shared__ int ts[256];
  int tid = threadIdx.x;
  int base = blockIdx.x*1024 + tid*4;
  int v[4]; int s = 0;
  #pragma unroll
  for (int k=0;k<4;k++){ int i=base+k; v[k] = (i<N) ? cnt[i] : 0; s += v[k]; }
  ts[tid] = s;
  __syncthreads();
  for (int off=1; off<256; off<<=1){
    int t = (tid>=off) ? ts[tid-off] : 0;
    __syncthreads();
    ts[tid] += t;
    __syncthreads();
  }
  int run = bsum[blockIdx.x] + ts[tid] - s;
  #pragma unroll
  for (int k=0;k<4;k++){ int i=base+k; if (i<N){ rowptr[i]=run; run += v[k]; } }
}

// ---- fused placement for both relations (uses pre-zeroed cnt2 buffers) ----
__global__ __launch_bounds__(256) void place2(const int* __restrict__ src, const int* __restrict__ dst,
    const int* __restrict__ rp_r, const int* __restrict__ rp_rb,
    int* __restrict__ cnt_p, int* __restrict__ cnt_c,
    int* __restrict__ si_r, int* __restrict__ si_rb, int E)
{
  int e = blockIdx.x*256 + threadIdx.x;
  if (e >= E) return;
  int s = src[e], d = dst[e];
  si_r [rp_r [d] + atomicAdd(&cnt_p[d], 1)] = s;
  si_rb[rp_rb[s] + atomicAdd(&cnt_c[s], 1)] = d;
}

// ---- aggregation: SINGLE PASS — num and denom accumulated together, x4 unroll ----
__global__ __launch_bounds__(256) void agg_kernel(
    const int* __restrict__ rowptr, const int* __restrict__ srcidx,
    const float* __restrict__ sSrc, const float* __restrict__ sDst,
    const unsigned short* __restrict__ H, unsigned short* __restrict__ out, int N)
{
  int wv = threadIdx.x >> 6, lane = threadIdx.x & 63;
  int n = blockIdx.x*4 + wv;
  if (n >= N) return;
  int e0 = rowptr[n], e1 = rowptr[n+1];
  int h = lane >> 3;                      // head of this lane's 4 columns
  float sdh = sDst[(long long)n*8 + h];
  float r0=0.f,r1=0.f,r2=0.f,r3=0.f, dA=0.f;
  float q0=0.f,q1=0.f,q2=0.f,q3=0.f, dB=0.f;
  float t0=0.f,t1=0.f,t2=0.f,t3=0.f, dC=0.f;
  float u0=0.f,u1=0.f,u2=0.f,u3=0.f, dD=0.f;
  int e = e0;
  for (; e+4 <= e1; e += 4){
    int sA = srcidx[e], sB = srcidx[e+1], sC = srcidx[e+2], sD = srcidx[e+3];
    float lA = sSrc[(long long)sA*8 + h] + sdh;
    float lB = sSrc[(long long)sB*8 + h] + sdh;
    float lC = sSrc[(long long)sC*8 + h] + sdh;
    float lD = sSrc[(long long)sD*8 + h] + sdh;
    uint2 uA = *(const uint2*)&H[(long long)sA*256 + lane*4];
    uint2 uB = *(const uint2*)&H[(long long)sB*256 + lane*4];
    uint2 uC = *(const uint2*)&H[(long long)sC*256 + lane*4];
    uint2 uD = *(const uint2*)&H[(long long)sD*256 + lane*4];
    float wA = __expf(lA > 0.f ? lA : 0.2f*lA);
    float wB = __expf(lB > 0.f ? lB : 0.2f*lB);
    float wC = __expf(lC > 0.f ? lC : 0.2f*lC);
    float wD = __expf(lD > 0.f ? lD : 0.2f*lD);
    dA += wA; dB += wB; dC += wC; dD += wD;
    r0 = fmaf(wA, b2f((unsigned short)(uA.x&0xffffu)), r0);
    r1 = fmaf(wA, b2f((unsigned short)(uA.x>>16)),     r1);
    r2 = fmaf(wA, b2f((unsigned short)(uA.y&0xffffu)), r2);
    r3 = fmaf(wA, b2f((unsigned short)(uA.y>>16)),     r3);
    q0 = fmaf(wB, b2f((unsigned short)(uB.x&0xffffu)), q0);
    q1 = fmaf(wB, b2f((unsigned short)(uB.x>>16)),     q1);
    q2 = fmaf(wB, b2f((unsigned short)(uB.y&0xffffu)), q2);
    q3 = fmaf(wB, b2f((unsigned short)(uB.y>>16)),     q3);
    t0 = fmaf(wC, b2f((unsigned short)(uC.x&0xffffu)), t0);
    t1 = fmaf(wC, b2f((unsigned short)(uC.x>>16)),     t1);
    t2 = fmaf(wC, b2f((unsigned short)(uC.y&0xffffu)), t2);
    t3 = fmaf(wC, b2f((unsigned short)(uC.y>>16)),     t3);
    u0 = fmaf(wD, b2f((unsigned short)(uD.x&0xffffu)), u0);
    u1 = fmaf(wD, b2f((unsigned short)(uD.x>>16)),     u1);
    u2 = fmaf(wD, b2f((unsigned short)(uD.y&0xffffu)), u2);
    u3 = fmaf(wD, b2f((unsigned short)(uD.y>>16)),     u3);
  }
  for (; e < e1; e++){
    int s = srcidx[e];
    float l = sSrc[(long long)s*8 + h] + sdh;
    float w = __expf(l > 0.f ? l : 0.2f*l);
    uint2 u = *(const uint2*)&H[(long long)s*256 + lane*4];
    dA += w;
    r0 = fmaf(w, b2f((unsigned short)(u.x&0xffffu)), r0);
    r1 = fmaf(w, b2f((unsigned short)(u.x>>16)),     r1);
    r2 = fmaf(w, b2f((unsigned short)(u.y&0xffffu)), r2);
    r3 = fmaf(w, b2f((unsigned short)(u.y>>16)),     r3);
  }
  float inv = 1.f/((dA+dB)+(dC+dD) + 1e-16f);
  r0 = (r0+q0+t0+u0)*inv; r1 = (r1+q1+t1+u1)*inv;
  r2 = (r2+q2+t2+u2)*inv; r3 = (r3+q3+t3+u3)*inv;
  uint2 o;
  o.x = (unsigned)f2b(fmaxf(r0,0.f)) | ((unsigned)f2b(fmaxf(r1,0.f))<<16);
  o.y = (unsigned)f2b(fmaxf(r2,0.f)) | ((unsigned)f2b(fmaxf(r3,0.f))<<16);
  *(uint2*)&out[(long long)n*256 + lane*4] = o;
}

// ---- Bt prep ----
__global__ __launch_bounds__(256) void prep_bt(const float* __restrict__ fc1W, unsigned short* __restrict__ Bt)
{
  int tid = blockIdx.x*256 + threadIdx.x;
  if (tid >= 128*544) return;
  int n = tid/544, k = tid%544;
  Bt[tid] = (k < 528) ? f2b(fc1W[k*128 + n]) : (unsigned short)0;
}

// ---- T1 (MFMA): 32 rows x 128 cols; ASYNC global_load_lds staging; row-major LDS ----
// feat row stride 552 halfwords: 512 graph | 16 emb | 16 zero | 8 pad (bank decorrelation)
__global__ __launch_bounds__(256) void fc1_mfma(
    const unsigned short* __restrict__ outC, const unsigned short* __restrict__ outP,
    const float* __restrict__ size_emb, const float* __restrict__ color_emb,
    const float* __restrict__ group_emb,
    const int* __restrict__ lsrc, const int* __restrict__ ldst,
    const int* __restrict__ sidx, const int* __restrict__ cidx, const int* __restrict__ gidx,
    const unsigned short* __restrict__ Bt, const float* __restrict__ fc1b,
    unsigned short* __restrict__ x1, float* __restrict__ bnsum)
{
  __shared__ unsigned short feat[32*552];   // 35328 B
  __shared__ float red[256];
  __shared__ int lsl[32], ldl[32], sil[32], cil[32], gil[32];
  int tid = threadIdx.x;
  int base = blockIdx.x*32;
  if (tid < 32){ lsl[tid]=lsrc[base+tid]; ldl[tid]=ldst[base+tid]; }
  else if (tid < 64){ int r=tid-32; sil[r]=sidx[base+r]; cil[r]=cidx[base+r]; gil[r]=gidx[base+r]; }
  __syncthreads();
  int wv = tid>>6, lane = tid&63;
  // one DMA per row: lanes 0-31 carry outC row (cols 0..255), lanes 32-63 outP row (256..511)
  #pragma unroll
  for (int i=0;i<8;i++){
    int r = wv*8 + i;
    const unsigned short* g = (lane < 32)
        ? (outC + (long long)lsl[r]*256 + lane*8)
        : (outP + (long long)ldl[r]*256 + (lane-32)*8);
    gl2lds16(g, &feat[r*552]);
  }
  // embeds: cols 512..527 + zero 528..543 (pad 544..551 never read)
  for (int idx=tid; idx<32*16; idx+=256){
    int r = idx>>4, q = idx&15;
    unsigned u = 0;
    if (q < 8){
      float v0, v1;
      int c0 = q*2;
      #pragma unroll
      for (int t=0;t<2;t++){
        int c = c0+t;
        float v;
        if (c<4)       v = size_emb [sil[r]*4 + c];
        else if (c<12) v = color_emb[cil[r]*8 + (c-4)];
        else           v = group_emb[gil[r]*4 + (c-12)];
        if (t==0) v0=v; else v1=v;
      }
      u = (unsigned)f2b(v0) | ((unsigned)f2b(v1)<<16);
    }
    *(unsigned*)&feat[r*552 + 512 + q*2] = u;
  }
  __syncthreads();   // drains DMA (vmcnt) + embed writes (lgkm)
  int m = lane&31, hi = lane>>5;
  f32x16 acc;
  #pragma unroll
  for (int i=0;i<16;i++) acc[i]=0.f;
  const unsigned short* ap  = feat + m*552 + hi*8;
  const unsigned short* btp = Bt + ((long long)(wv*32 + m))*544 + hi*8;
  bf16x8 bcur = *(const bf16x8*)(btp);
  #pragma unroll 2
  for (int ks=0; ks<34; ks++){
    bf16x8 bnext = (ks<33) ? *(const bf16x8*)(btp + (ks+1)*16) : bcur;
    bf16x8 a = *(const bf16x8*)(ap + ks*16);
    acc = __builtin_amdgcn_mfma_f32_32x32x16_bf16(a, bcur, acc, 0, 0, 0);
    bcur = bnext;
  }
  int col = wv*32 + m;
  float bias = fc1b[col];
  float s=0.f, q=0.f;
  #pragma unroll
  for (int reg=0; reg<16; reg++){
    int row = (reg&3) + 8*(reg>>2) + 4*hi;
    float v = fmaxf(acc[reg] + bias, 0.f);
    x1[(long long)(base+row)*128 + col] = f2b(v);
    s += v; q += v*v;
  }
  s += __shfl_xor(s, 32);
  q += __shfl_xor(q, 32);
  if (hi == 0){ red[col] = s; red[128+col] = q; }
  __syncthreads();
  if (tid < 128){
    atomicAdd(&bnsum[tid],     red[tid]);
    atomicAdd(&bnsum[128+tid], red[128+tid]);
  }
}

// ---- T2: fold BN1 into fc2 ----
__global__ void bn1_fold(const float* __restrict__ bnsum,
    const float* __restrict__ gamma, const float* __restrict__ beta,
    const float* __restrict__ fc2W, const float* __restrict__ fc2b,
    float* __restrict__ fc2p, float* __restrict__ b2p, float invB)
{
  __shared__ float sc[128], sh[128];
  int tid = threadIdx.x;
  if (tid<128){
    float mu  = bnsum[tid]*invB;
    float var = bnsum[128+tid]*invB - mu*mu;
    float s = gamma[tid] * rsqrtf(var + 1e-5f);
    sc[tid]=s; sh[tid]= beta[tid] - mu*s;
  }
  __syncthreads();
  for (int idx=tid; idx<128*32; idx+=256){ int k=idx>>5; fc2p[idx] = sc[k]*fc2W[idx]; }
  if (tid<32){
    float a = fc2b[tid];
    for (int k=0;k<128;k++) a = fmaf(sh[k], fc2W[k*32+tid], a);
    b2p[tid]=a;
  }
}

// ---- T3: x2 = relu(x1 @ fc2' + b2') bf16, BN2 stats ----
__global__ __launch_bounds__(256) void fc2_kernel(const unsigned short* __restrict__ x1,
    const float* __restrict__ fc2p, const float* __restrict__ b2p,
    unsigned short* __restrict__ x2, float* __restrict__ bnsum2)
{
  __shared__ float xt[64*128];
  __shared__ float Wl[128*32];
  __shared__ float redS[8][32];
  __shared__ float redQ[8][32];
  int tid = threadIdx.x;
  for (int idx=tid; idx<4096; idx+=256) Wl[idx]=fc2p[idx];
  long long base = (long long)blockIdx.x*64;
  const unsigned* x1u = (const unsigned*)x1;
  for (int idx=tid; idx<64*64; idx+=256){
    unsigned u = x1u[base*64 + idx];
    xt[idx*2]   = b2f((unsigned short)(u&0xffffu));
    xt[idx*2+1] = b2f((unsigned short)(u>>16));
  }
  __syncthreads();
  int tx=tid&31, ty=tid>>5;
  float acc[8];
  float bb=b2p[tx];
  #pragma unroll
  for (int i=0;i<8;i++) acc[i]=bb;
  for (int k=0;k<128;k++){
    float w=Wl[k*32+tx];
    #pragma unroll
    for (int i=0;i<8;i++) acc[i]=fmaf(xt[(ty*8+i)*128+k], w, acc[i]);
  }
  float s=0,q=0;
  #pragma unroll
  for (int i=0;i<8;i++){
    float v=fmaxf(acc[i],0.f);
    x2[(base+ty*8+i)*32+tx]=f2b(v);
    s+=v; q+=v*v;
  }
  redS[ty][tx]=s; redQ[ty][tx]=q;
  __syncthreads();
  if (tid<32){
    float a=0,b=0;
    #pragma unroll
    for (int j=0;j<8;j++){ a+=redS[j][tid]; b+=redQ[j][tid]; }
    atomicAdd(&bnsum2[tid],a); atomicAdd(&bnsum2[32+tid],b);
  }
}

// ---- T4: fold BN2 into fc3 ----
__global__ void bn2_fold(const float* __restrict__ bnsum2,
    const float* __restrict__ gamma2, const float* __restrict__ beta2,
    const float* __restrict__ fc3W, const float* __restrict__ fc3b,
    float* __restrict__ w3p, float invB)
{
  __shared__ float sh3[32];
  int tid = threadIdx.x;
  if (tid<32){
    float mu  = bnsum2[tid]*invB;
    float var = bnsum2[32+tid]*invB - mu*mu;
    float s   = gamma2[tid] * rsqrtf(var + 1e-5f);
    float shv = beta2[tid] - mu*s;
    float w   = fc3W[tid];
    w3p[tid]  = s*w;
    sh3[tid]  = shv*w;
  }
  __syncthreads();
  if (tid==0){
    float a = fc3b[0];
    for (int j=0;j<32;j++) a += sh3[j];
    w3p[32] = a;
  }
}

// ---- T5: out = x2 @ w3' + b3' (fp32 out) ----
__global__ __launch_bounds__(256) void fc3_kernel(const unsigned short* __restrict__ x2,
    const float* __restrict__ w3p, float* __restrict__ out)
{
  __shared__ float wl[34];
  int tid = threadIdx.x;
  if (tid<33) wl[tid]=w3p[tid];
  __syncthreads();
  long long row = (long long)blockIdx.x*32 + (tid>>3);
  int j0 = (tid&7)*4;
  uint2 u = *(const uint2*)(x2 + row*32 + j0);
  float a = b2f((unsigned short)(u.x&0xffffu))*wl[j0]
          + b2f((unsigned short)(u.x>>16))   *wl[j0+1]
          + b2f((unsigned short)(u.y&0xffffu))*wl[j0+2]
          + b2f((unsigned short)(u.y>>16))   *wl[j0+3];
  a += __shfl_xor(a,1);
  a += __shfl_xor(a,2);
  a += __shfl_xor(a,4);
  if ((tid&7)==0) out[row] = a + wl[32];
}

extern "C" void kernel_launch(void* const* d_in, const int* in_sizes, int n_in,
                              void* d_out, int out_size, void* d_ws, size_t ws_size,
                              hipStream_t stream)
{
  (void)in_sizes; (void)n_in; (void)out_size; (void)ws_size;
  const float* customer_x = (const float*)d_in[0];
  const float* product_x  = (const float*)d_in[1];
  const float* pcW = (const float*)d_in[2];
  const float* pcB = (const float*)d_in[3];
  const float* ppW = (const float*)d_in[4];
  const float* ppB = (const float*)d_in[5];
  const float* att_src_r  = (const float*)d_in[6];
  const float* att_dst_r  = (const float*)d_in[7];
  const float* att_src_rb = (const float*)d_in[8];
  const float* att_dst_rb = (const float*)d_in[9];
  // d_in[10..12] dead (semantic softmax over 1 metapath == 1)
  const float* color_emb = (const float*)d_in[13];
  const float* size_emb  = (const float*)d_in[14];
  const float* group_emb = (const float*)d_in[15];
  const float* fc1W = (const float*)d_in[16];
  const float* fc1b = (const float*)d_in[17];
  const float* fc2W = (const float*)d_in[18];
  const float* fc2b = (const float*)d_in[19];
  const float* fc3W = (const float*)d_in[20];
  const float* fc3b = (const float*)d_in[21];
  const float* bn1g = (const float*)d_in[22];
  const float* bn1b = (const float*)d_in[23];
  const float* bn2g = (const float*)d_in[24];
  const float* bn2b = (const float*)d_in[25];
  const int* edge_src  = (const int*)d_in[26];
  const int* edge_dst  = (const int*)d_in[27];
  const int* label_src = (const int*)d_in[28];
  const int* label_dst = (const int*)d_in[29];
  const int* size_idx  = (const int*)d_in[30];
  const int* color_idx = (const int*)d_in[31];
  const int* group_idx = (const int*)d_in[32];

  char* ws = (char*)d_ws;
  size_t off = 0;
  auto alloc = [&](size_t bytes)->char* {
    char* p = ws + off;
    off += (bytes + 255) & ~(size_t)255;
    return p;
  };
  // ~234 MB peak (< 256 MiB hard limit per R1/R2 fault evidence)
  unsigned short* H_c  = (unsigned short*)alloc((size_t)NCC*256*2);   // 102.4 MB; out_c aliases after agg_r
  unsigned short* H_p  = (unsigned short*)alloc((size_t)NPRR*256*2);  // 51.2 MB; x1b aliases after agg_rb
  unsigned short* out_p= (unsigned short*)alloc((size_t)NPRR*256*2);  // 51.2 MB
  float* s_cr     = (float*)alloc((size_t)NCC*8*4);     // 6.4 MB (x2b aliases after aggs)
  float* s_crb    = (float*)alloc((size_t)NCC*8*4);     // 6.4 MB
  float* s_pr     = (float*)alloc((size_t)NPRR*8*4);    // 3.2 MB
  float* s_prb    = (float*)alloc((size_t)NPRR*8*4);    // 3.2 MB
  int* rowptr_r   = (int*)alloc((size_t)(NPRR+1)*4);
  int* rowptr_rb  = (int*)alloc((size_t)(NCC+1)*4);
  int* srcidx_r   = (int*)alloc((size_t)NEE*4);         // 2 MB
  int* srcidx_rb  = (int*)alloc((size_t)NEE*4);         // 2 MB
  // all 4 counter buffers in ONE allocation — contiguous, memset length exact (R10 fix)
  int* cnts       = (int*)alloc((size_t)(NCC+NPRR)*2*4);
  int* cnt_c      = cnts;
  int* cnt_p      = cnts + NCC;
  int* cnt_c2     = cnts + NCC + NPRR;
  int* cnt_p2     = cnts + NCC + NPRR + NCC;
  int* bsum_c     = (int*)alloc(256*4);
  int* bsum_p     = (int*)alloc(256*4);
  unsigned short* Bt = (unsigned short*)alloc(128*544*2);
  float* wa_c   = (float*)alloc(272*4);
  float* wa_p   = (float*)alloc(272*4);
  float* bnsum1 = (float*)alloc(256*4);
  float* bnsum2 = (float*)alloc(64*4);
  float* fc2p   = (float*)alloc(4096*4);
  float* b2p    = (float*)alloc(32*4);
  float* w3p    = (float*)alloc(34*4);
  unsigned short* out_c = H_c;                   // H_c dead after agg_r
  unsigned short* x1b   = H_p;                   // H_p dead after agg_rb
  unsigned short* x2b   = (unsigned short*)s_cr; // scores dead after aggs

  hipMemsetAsync(bnsum1, 0, 1280, stream);       // bnsum1+bnsum2 contiguous
  hipMemsetAsync(cnts, 0, (size_t)(NCC+NPRR)*2*4, stream);

  // scores via algebraic fusion
  wa_prep<<<1,256,0,stream>>>(pcW, pcB, att_src_r, att_dst_rb, wa_c);
  wa_prep<<<1,256,0,stream>>>(ppW, ppB, att_dst_r, att_src_rb, wa_p);
  score_kernel<<<(NCC +255)/256,256,0,stream>>>(customer_x, wa_c, s_cr, s_crb, NCC);
  score_kernel<<<(NPRR+255)/256,256,0,stream>>>(product_x,  wa_p, s_pr, s_prb, NPRR);

  // projections -> bf16 H
  proj_kernel<<<2048,256,0,stream>>>(customer_x, pcW, pcB, H_c, NCC);
  proj_kernel<<<2048,256,0,stream>>>(product_x,  ppW, ppB, H_p, NPRR);

  // CSR build (both relations)
  const int eg = (NEE+255)/256;
  const int BP = (NPRR+1023)/1024;   // 98
  const int BC = (NCC +1023)/1024;   // 196
  hist2<<<eg,256,0,stream>>>(edge_src, edge_dst, cnt_c, cnt_p, NEE);
  scan_phase1<<<BP,256,0,stream>>>(cnt_p, bsum_p, NPRR);
  scan_phase2<<<1,256,0,stream>>>(bsum_p, BP, rowptr_r, NPRR);
  scan_phase3<<<BP,256,0,stream>>>(cnt_p, bsum_p, rowptr_r, NPRR);
  scan_phase1<<<BC,256,0,stream>>>(cnt_c, bsum_c, NCC);
  scan_phase2<<<1,256,0,stream>>>(bsum_c, BC, rowptr_rb, NCC);
  scan_phase3<<<BC,256,0,stream>>>(cnt_c, bsum_c, rowptr_rb, NCC);
  place2<<<eg,256,0,stream>>>(edge_src, edge_dst, rowptr_r, rowptr_rb,
      cnt_p2, cnt_c2, srcidx_r, srcidx_rb, NEE);

  // single-pass gather aggregation (no atomics)
  agg_kernel<<<(NPRR+3)/4,256,0,stream>>>(rowptr_r,  srcidx_r,  s_cr,  s_pr,  H_c, out_p, NPRR);
  agg_kernel<<<(NCC +3)/4,256,0,stream>>>(rowptr_rb, srcidx_rb, s_prb, s_crb, H_p, out_c, NCC);

  // tail MLP: MFMA fc1 (async DMA staging) + folded BN
  prep_bt<<<(128*544+255)/256,256,0,stream>>>(fc1W, Bt);
  fc1_mfma<<<NBB/32,256,0,stream>>>(out_c, out_p, size_emb, color_emb, group_emb,
      label_src, label_dst, size_idx, color_idx, group_idx, Bt, fc1b, x1b, bnsum1);
  bn1_fold<<<1,256,0,stream>>>(bnsum1, bn1g, bn1b, fc2W, fc2b, fc2p, b2p, 1.0f/NBB);
  fc2_kernel<<<NBB/64,256,0,stream>>>(x1b, fc2p, b2p, x2b, bnsum2);
  bn2_fold<<<1,64,0,stream>>>(bnsum2, bn2g, bn2b, fc3W, fc3b, w3p, 1.0f/NBB);
  fc3_kernel<<<NBB/32,256,0,stream>>>(x2b, w3p, (float*)d_out);
}

// Round 13
// 760.270 us; speedup vs baseline: 1.1116x; 1.0230x over previous
//
#include <hip/hip_runtime.h>

#define NCC 200000
#define NPRR 100000
#define NEE 500000
#define NBB 200000

typedef __attribute__((ext_vector_type(8))) short bf16x8;
typedef __attribute__((ext_vector_type(16))) float f32x16;

__device__ __forceinline__ float b2f(unsigned short u){ return __uint_as_float(((unsigned)u)<<16); }
__device__ __forceinline__ unsigned short f2b(float f){
  unsigned x = __float_as_uint(f);
  return (unsigned short)((x + 0x7fffu + ((x>>16)&1u)) >> 16);
}
// async global->LDS DMA, 16B/lane; LDS dest = uniform base + lane*16 (HW)
__device__ __forceinline__ void gl2lds16(const void* g, void* l){
  __builtin_amdgcn_global_load_lds(
      (const __attribute__((address_space(1))) unsigned int*)g,
      (__attribute__((address_space(3))) unsigned int*)l, 16, 0, 0);
}

// ---- WA prep (both node types in one launch): WA[set][k][h] ----
__global__ __launch_bounds__(256) void wa_prep2(
    const float* __restrict__ Wc, const float* __restrict__ bc,
    const float* __restrict__ attAc, const float* __restrict__ attBc,
    const float* __restrict__ Wp, const float* __restrict__ bp,
    const float* __restrict__ attAp, const float* __restrict__ attBp,
    float* __restrict__ WAc, float* __restrict__ WAp)
{
  int tid = threadIdx.x;
  for (int task = tid; task < 4*17*8; task += 256) {
    int grp = task / 136, rem = task % 136;   // grp: 0,1 = customer A/B; 2,3 = product A/B
    int k = rem >> 3, h = rem & 7;
    const float* att = (grp==0)?attAc:(grp==1)?attBc:(grp==2)?attAp:attBp;
    const float* W   = (grp<2)?Wc:Wp;
    const float* bias= (grp<2)?bc:bp;
    const float* row = (k < 16) ? (W + k*256) : bias;
    float acc = 0.f;
    for (int d = 0; d < 32; d++) acc = fmaf(row[h*32+d], att[h*32+d], acc);
    if (grp<2) WAc[(grp&1)*136 + rem] = acc;
    else       WAp[(grp&1)*136 + rem] = acc;
  }
}

// ---- projection + fused scores: H=X@W+b (bf16), sA/sB = x·(W@att)+b·att ----
__global__ __launch_bounds__(256) void proj_kernel(const float* __restrict__ X,
    const float* __restrict__ W, const float* __restrict__ b,
    const float* __restrict__ WA,
    unsigned short* __restrict__ H, float* __restrict__ sA, float* __restrict__ sB, int N)
{
  __shared__ float Wl[16*256];
  __shared__ float bl[256];
  __shared__ float xs[8*16];
  __shared__ float wa[272];
  int tid = threadIdx.x;
  #pragma unroll
  for (int i=0;i<16;i++) Wl[i*256+tid] = W[i*256+tid];
  bl[tid] = b[tid];
  for (int i=tid;i<272;i+=256) wa[i]=WA[i];
  int nh = tid>>7;
  int c2 = (tid&127)*2;
  for (int base = blockIdx.x*8; base < N; base += gridDim.x*8) {
    __syncthreads();
    if (tid < 128) {
      int n = tid>>4, k = tid&15;
      int node = base + n;
      xs[tid] = (node < N) ? X[(long long)node*16+k] : 0.f;
    }
    __syncthreads();
    // scores: 128 tasks = 8 nodes x 2 sets x 8 heads
    if (tid < 128){
      int nn = tid>>4, t = tid&15;
      int set = t>>3, h = t&7;
      int node = base + nn;
      if (node < N){
        const float* w = wa + set*136;
        float a = w[128 + h];
        #pragma unroll
        for (int k=0;k<16;k++) a = fmaf(xs[nn*16+k], w[k*8+h], a);
        (set ? sB : sA)[(long long)node*8 + h] = a;
      }
    }
    #pragma unroll
    for (int np=0;np<4;np++){
      int n = np*2 + nh;
      int node = base+n;
      if (node < N){
        float a0 = bl[c2], a1 = bl[c2+1];
        #pragma unroll
        for (int k=0;k<16;k++){
          float xv = xs[n*16+k];
          a0 = fmaf(xv, Wl[k*256+c2],   a0);
          a1 = fmaf(xv, Wl[k*256+c2+1], a1);
        }
        *(unsigned*)&H[(long long)node*256 + c2] = (unsigned)f2b(a0) | ((unsigned)f2b(a1)<<16);
      }
    }
  }
}

// ---- fused degree histogram for both relations ----
__global__ __launch_bounds__(256) void hist2(const int* __restrict__ src, const int* __restrict__ dst,
    int* __restrict__ cnt_c, int* __restrict__ cnt_p, int E)
{
  int e = blockIdx.x*256 + threadIdx.x;
  if (e >= E) return;
  atomicAdd(&cnt_p[dst[e]], 1);
  atomicAdd(&cnt_c[src[e]], 1);
}

// ---- hierarchical exclusive scan ----
__global__ __launch_bounds__(256) void scan_phase1(const int* __restrict__ cnt, int* __restrict__ bsum, int N)
{
  __shared__ int red[256];
  int tid = threadIdx.x;
  int base = blockIdx.x*1024 + tid*4;
  int s = 0;
  #pragma unroll
  for (int k=0;k<4;k++){ int i=base+k; if (i<N) s += cnt[i]; }
  red[tid] = s;
  __syncthreads();
  for (int off=128; off>0; off>>=1){ if (tid<off) red[tid]+=red[tid+off]; __syncthreads(); }
  if (tid==0) bsum[blockIdx.x] = red[0];
}

__global__ __launch_bounds__(256) void scan_phase2(int* __restrict__ bsum, int B,
    int* __restrict__ rowptr, int N)
{
  __shared__ int ts[256];
  int tid = threadIdx.x;
  int v = (tid<B) ? bsum[tid] : 0;
  ts[tid] = v;
  __syncthreads();
  for (int off=1; off<256; off<<=1){
    int t = (tid>=off) ? ts[tid-off] : 0;
    __syncthreads();
    ts[tid] += t;
    __syncthreads();
  }
  if (tid < B) bsum[tid] = ts[tid] - v;
  if (tid == B-1) rowptr[N] = ts[tid];
}

__global__ __launch_bounds__(256) void scan_phase3(const int* __restrict__ cnt,
    const int* __restrict__ bsum, int* __restrict__ rowptr, int N)
{
  __shared__ int ts[256];
  int tid = threadIdx.x;
  int base = blockIdx.x*1024 + tid*4;
  int v[4]; int s = 0;
  #pragma unroll
  for (int k=0;k<4;k++){ int i=base+k; v[k] = (i<N) ? cnt[i] : 0; s += v[k]; }
  ts[tid] = s;
  __syncthreads();
  for (int off=1; off<256; off<<=1){
    int t = (tid>=off) ? ts[tid-off] : 0;
    __syncthreads();
    ts[tid] += t;
    __syncthreads();
  }
  int run = bsum[blockIdx.x] + ts[tid] - s;
  #pragma unroll
  for (int k=0;k<4;k++){ int i=base+k; if (i<N){ rowptr[i]=run; run += v[k]; } }
}

// ---- fused placement for both relations (uses pre-zeroed cnt2 buffers) ----
__global__ __launch_bounds__(256) void place2(const int* __restrict__ src, const int* __restrict__ dst,
    const int* __restrict__ rp_r, const int* __restrict__ rp_rb,
    int* __restrict__ cnt_p, int* __restrict__ cnt_c,
    int* __restrict__ si_r, int* __restrict__ si_rb, int E)
{
  int e = blockIdx.x*256 + threadIdx.x;
  if (e >= E) return;
  int s = src[e], d = dst[e];
  si_r [rp_r [d] + atomicAdd(&cnt_p[d], 1)] = s;
  si_rb[rp_rb[s] + atomicAdd(&cnt_c[s], 1)] = d;
}

// ---- aggregation v2: lanes split (side, colgroup); uint4 row loads; single pass ----
// lane = side*32 + j; side 0 handles even edges, side 1 odd; lane covers cols j*8..j*8+7
__global__ __launch_bounds__(256) void agg_kernel(
    const int* __restrict__ rowptr, const int* __restrict__ srcidx,
    const float* __restrict__ sSrc, const float* __restrict__ sDst,
    const unsigned short* __restrict__ H, unsigned short* __restrict__ out, int N)
{
  int wv = threadIdx.x >> 6, lane = threadIdx.x & 63;
  int n = blockIdx.x*4 + wv;
  if (n >= N) return;
  int e0 = rowptr[n], e1 = rowptr[n+1];
  int j = lane & 31;
  int side = lane >> 5;
  int h = j >> 2;                         // head for cols j*8..j*8+7
  float sdh = sDst[(long long)n*8 + h];
  float a0=0,a1=0,a2=0,a3=0,a4=0,a5=0,a6=0,a7=0, da=0.f;
  float b0=0,b1=0,b2=0,b3=0,b4=0,b5=0,b6=0,b7=0, db=0.f;
  int e = e0 + side;
  for (; e + 2 < e1; e += 4){             // two edges per lane in flight
    int sA = srcidx[e], sB = srcidx[e+2];
    float lA = sSrc[(long long)sA*8 + h] + sdh;
    float lB = sSrc[(long long)sB*8 + h] + sdh;
    uint4 uA = *(const uint4*)&H[(long long)sA*256 + j*8];
    uint4 uB = *(const uint4*)&H[(long long)sB*256 + j*8];
    float wA = __expf(lA > 0.f ? lA : 0.2f*lA);
    float wB = __expf(lB > 0.f ? lB : 0.2f*lB);
    da += wA; db += wB;
    a0 = fmaf(wA, b2f((unsigned short)(uA.x&0xffffu)), a0);
    a1 = fmaf(wA, b2f((unsigned short)(uA.x>>16)),     a1);
    a2 = fmaf(wA, b2f((unsigned short)(uA.y&0xffffu)), a2);
    a3 = fmaf(wA, b2f((unsigned short)(uA.y>>16)),     a3);
    a4 = fmaf(wA, b2f((unsigned short)(uA.z&0xffffu)), a4);
    a5 = fmaf(wA, b2f((unsigned short)(uA.z>>16)),     a5);
    a6 = fmaf(wA, b2f((unsigned short)(uA.w&0xffffu)), a6);
    a7 = fmaf(wA, b2f((unsigned short)(uA.w>>16)),     a7);
    b0 = fmaf(wB, b2f((unsigned short)(uB.x&0xffffu)), b0);
    b1 = fmaf(wB, b2f((unsigned short)(uB.x>>16)),     b1);
    b2 = fmaf(wB, b2f((unsigned short)(uB.y&0xffffu)), b2);
    b3 = fmaf(wB, b2f((unsigned short)(uB.y>>16)),     b3);
    b4 = fmaf(wB, b2f((unsigned short)(uB.z&0xffffu)), b4);
    b5 = fmaf(wB, b2f((unsigned short)(uB.z>>16)),     b5);
    b6 = fmaf(wB, b2f((unsigned short)(uB.w&0xffffu)), b6);
    b7 = fmaf(wB, b2f((unsigned short)(uB.w>>16)),     b7);
  }
  for (; e < e1; e += 2){
    int s = srcidx[e];
    float l = sSrc[(long long)s*8 + h] + sdh;
    uint4 u = *(const uint4*)&H[(long long)s*256 + j*8];
    float w = __expf(l > 0.f ? l : 0.2f*l);
    da += w;
    a0 = fmaf(w, b2f((unsigned short)(u.x&0xffffu)), a0);
    a1 = fmaf(w, b2f((unsigned short)(u.x>>16)),     a1);
    a2 = fmaf(w, b2f((unsigned short)(u.y&0xffffu)), a2);
    a3 = fmaf(w, b2f((unsigned short)(u.y>>16)),     a3);
    a4 = fmaf(w, b2f((unsigned short)(u.z&0xffffu)), a4);
    a5 = fmaf(w, b2f((unsigned short)(u.z>>16)),     a5);
    a6 = fmaf(w, b2f((unsigned short)(u.w&0xffffu)), a6);
    a7 = fmaf(w, b2f((unsigned short)(u.w>>16)),     a7);
  }
  a0+=b0; a1+=b1; a2+=b2; a3+=b3; a4+=b4; a5+=b5; a6+=b6; a7+=b7;
  da += db;
  // combine the two sides (other side's partial sums for same cols)
  a0 += __shfl_xor(a0,32); a1 += __shfl_xor(a1,32);
  a2 += __shfl_xor(a2,32); a3 += __shfl_xor(a3,32);
  a4 += __shfl_xor(a4,32); a5 += __shfl_xor(a5,32);
  a6 += __shfl_xor(a6,32); a7 += __shfl_xor(a7,32);
  da += __shfl_xor(da,32);
  float inv = 1.f/(da + 1e-16f);
  if (side == 0){
    uint4 o;
    o.x = (unsigned)f2b(fmaxf(a0*inv,0.f)) | ((unsigned)f2b(fmaxf(a1*inv,0.f))<<16);
    o.y = (unsigned)f2b(fmaxf(a2*inv,0.f)) | ((unsigned)f2b(fmaxf(a3*inv,0.f))<<16);
    o.z = (unsigned)f2b(fmaxf(a4*inv,0.f)) | ((unsigned)f2b(fmaxf(a5*inv,0.f))<<16);
    o.w = (unsigned)f2b(fmaxf(a6*inv,0.f)) | ((unsigned)f2b(fmaxf(a7*inv,0.f))<<16);
    *(uint4*)&out[(long long)n*256 + j*8] = o;
  }
}

// ---- Bt prep ----
__global__ __launch_bounds__(256) void prep_bt(const float* __restrict__ fc1W, unsigned short* __restrict__ Bt)
{
  int tid = blockIdx.x*256 + threadIdx.x;
  if (tid >= 128*544) return;
  int n = tid/544, k = tid%544;
  Bt[tid] = (k < 528) ? f2b(fc1W[k*128 + n]) : (unsigned short)0;
}

// ---- T1 (MFMA): 32 rows x 128 cols; ASYNC global_load_lds staging; row-major LDS ----
__global__ __launch_bounds__(256) void fc1_mfma(
    const unsigned short* __restrict__ outC, const unsigned short* __restrict__ outP,
    const float* __restrict__ size_emb, const float* __restrict__ color_emb,
    const float* __restrict__ group_emb,
    const int* __restrict__ lsrc, const int* __restrict__ ldst,
    const int* __restrict__ sidx, const int* __restrict__ cidx, const int* __restrict__ gidx,
    const unsigned short* __restrict__ Bt, const float* __restrict__ fc1b,
    unsigned short* __restrict__ x1, float* __restrict__ bnsum)
{
  __shared__ unsigned short feat[32*552];   // 35328 B
  __shared__ float red[256];
  __shared__ int lsl[32], ldl[32], sil[32], cil[32], gil[32];
  int tid = threadIdx.x;
  int base = blockIdx.x*32;
  if (tid < 32){ lsl[tid]=lsrc[base+tid]; ldl[tid]=ldst[base+tid]; }
  else if (tid < 64){ int r=tid-32; sil[r]=sidx[base+r]; cil[r]=cidx[base+r]; gil[r]=gidx[base+r]; }
  __syncthreads();
  int wv = tid>>6, lane = tid&63;
  #pragma unroll
  for (int i=0;i<8;i++){
    int r = wv*8 + i;
    const unsigned short* g = (lane < 32)
        ? (outC + (long long)lsl[r]*256 + lane*8)
        : (outP + (long long)ldl[r]*256 + (lane-32)*8);
    gl2lds16(g, &feat[r*552]);
  }
  for (int idx=tid; idx<32*16; idx+=256){
    int r = idx>>4, q = idx&15;
    unsigned u = 0;
    if (q < 8){
      float v0, v1;
      int c0 = q*2;
      #pragma unroll
      for (int t=0;t<2;t++){
        int c = c0+t;
        float v;
        if (c<4)       v = size_emb [sil[r]*4 + c];
        else if (c<12) v = color_emb[cil[r]*8 + (c-4)];
        else           v = group_emb[gil[r]*4 + (c-12)];
        if (t==0) v0=v; else v1=v;
      }
      u = (unsigned)f2b(v0) | ((unsigned)f2b(v1)<<16);
    }
    *(unsigned*)&feat[r*552 + 512 + q*2] = u;
  }
  __syncthreads();
  int m = lane&31, hi = lane>>5;
  f32x16 acc;
  #pragma unroll
  for (int i=0;i<16;i++) acc[i]=0.f;
  const unsigned short* ap  = feat + m*552 + hi*8;
  const unsigned short* btp = Bt + ((long long)(wv*32 + m))*544 + hi*8;
  bf16x8 bcur = *(const bf16x8*)(btp);
  #pragma unroll 2
  for (int ks=0; ks<34; ks++){
    bf16x8 bnext = (ks<33) ? *(const bf16x8*)(btp + (ks+1)*16) : bcur;
    bf16x8 a = *(const bf16x8*)(ap + ks*16);
    acc = __builtin_amdgcn_mfma_f32_32x32x16_bf16(a, bcur, acc, 0, 0, 0);
    bcur = bnext;
  }
  int col = wv*32 + m;
  float bias = fc1b[col];
  float s=0.f, q=0.f;
  #pragma unroll
  for (int reg=0; reg<16; reg++){
    int row = (reg&3) + 8*(reg>>2) + 4*hi;
    float v = fmaxf(acc[reg] + bias, 0.f);
    x1[(long long)(base+row)*128 + col] = f2b(v);
    s += v; q += v*v;
  }
  s += __shfl_xor(s, 32);
  q += __shfl_xor(q, 32);
  if (hi == 0){ red[col] = s; red[128+col] = q; }
  __syncthreads();
  if (tid < 128){
    atomicAdd(&bnsum[tid],     red[tid]);
    atomicAdd(&bnsum[128+tid], red[128+tid]);
  }
}

// ---- T2: fold BN1 into fc2 ----
__global__ void bn1_fold(const float* __restrict__ bnsum,
    const float* __restrict__ gamma, const float* __restrict__ beta,
    const float* __restrict__ fc2W, const float* __restrict__ fc2b,
    float* __restrict__ fc2p, float* __restrict__ b2p, float invB)
{
  __shared__ float sc[128], sh[128];
  int tid = threadIdx.x;
  if (tid<128){
    float mu  = bnsum[tid]*invB;
    float var = bnsum[128+tid]*invB - mu*mu;
    float s = gamma[tid] * rsqrtf(var + 1e-5f);
    sc[tid]=s; sh[tid]= beta[tid] - mu*s;
  }
  __syncthreads();
  for (int idx=tid; idx<128*32; idx+=256){ int k=idx>>5; fc2p[idx] = sc[k]*fc2W[idx]; }
  if (tid<32){
    float a = fc2b[tid];
    for (int k=0;k<128;k++) a = fmaf(sh[k], fc2W[k*32+tid], a);
    b2p[tid]=a;
  }
}

// ---- T3: x2 = relu(x1 @ fc2' + b2') bf16, BN2 stats ----
__global__ __launch_bounds__(256) void fc2_kernel(const unsigned short* __restrict__ x1,
    const float* __restrict__ fc2p, const float* __restrict__ b2p,
    unsigned short* __restrict__ x2, float* __restrict__ bnsum2)
{
  __shared__ float xt[64*128];
  __shared__ float Wl[128*32];
  __shared__ float redS[8][32];
  __shared__ float redQ[8][32];
  int tid = threadIdx.x;
  for (int idx=tid; idx<4096; idx+=256) Wl[idx]=fc2p[idx];
  long long base = (long long)blockIdx.x*64;
  const unsigned* x1u = (const unsigned*)x1;
  for (int idx=tid; idx<64*64; idx+=256){
    unsigned u = x1u[base*64 + idx];
    xt[idx*2]   = b2f((unsigned short)(u&0xffffu));
    xt[idx*2+1] = b2f((unsigned short)(u>>16));
  }
  __syncthreads();
  int tx=tid&31, ty=tid>>5;
  float acc[8];
  float bb=b2p[tx];
  #pragma unroll
  for (int i=0;i<8;i++) acc[i]=bb;
  for (int k=0;k<128;k++){
    float w=Wl[k*32+tx];
    #pragma unroll
    for (int i=0;i<8;i++) acc[i]=fmaf(xt[(ty*8+i)*128+k], w, acc[i]);
  }
  float s=0,q=0;
  #pragma unroll
  for (int i=0;i<8;i++){
    float v=fmaxf(acc[i],0.f);
    x2[(base+ty*8+i)*32+tx]=f2b(v);
    s+=v; q+=v*v;
  }
  redS[ty][tx]=s; redQ[ty][tx]=q;
  __syncthreads();
  if (tid<32){
    float a=0,b=0;
    #pragma unroll
    for (int j=0;j<8;j++){ a+=redS[j][tid]; b+=redQ[j][tid]; }
    atomicAdd(&bnsum2[tid],a); atomicAdd(&bnsum2[32+tid],b);
  }
}

// ---- T4: fold BN2 into fc3 ----
__global__ void bn2_fold(const float* __restrict__ bnsum2,
    const float* __restrict__ gamma2, const float* __restrict__ beta2,
    const float* __restrict__ fc3W, const float* __restrict__ fc3b,
    float* __restrict__ w3p, float invB)
{
  __shared__ float sh3[32];
  int tid = threadIdx.x;
  if (tid<32){
    float mu  = bnsum2[tid]*invB;
    float var = bnsum2[32+tid]*invB - mu*mu;
    float s   = gamma2[tid] * rsqrtf(var + 1e-5f);
    float shv = beta2[tid] - mu*s;
    float w   = fc3W[tid];
    w3p[tid]  = s*w;
    sh3[tid]  = shv*w;
  }
  __syncthreads();
  if (tid==0){
    float a = fc3b[0];
    for (int j=0;j<32;j++) a += sh3[j];
    w3p[32] = a;
  }
}

// ---- T5: out = x2 @ w3' + b3' (fp32 out) ----
__global__ __launch_bounds__(256) void fc3_kernel(const unsigned short* __restrict__ x2,
    const float* __restrict__ w3p, float* __restrict__ out)
{
  __shared__ float wl[34];
  int tid = threadIdx.x;
  if (tid<33) wl[tid]=w3p[tid];
  __syncthreads();
  long long row = (long long)blockIdx.x*32 + (tid>>3);
  int j0 = (tid&7)*4;
  uint2 u = *(const uint2*)(x2 + row*32 + j0);
  float a = b2f((unsigned short)(u.x&0xffffu))*wl[j0]
          + b2f((unsigned short)(u.x>>16))   *wl[j0+1]
          + b2f((unsigned short)(u.y&0xffffu))*wl[j0+2]
          + b2f((unsigned short)(u.y>>16))   *wl[j0+3];
  a += __shfl_xor(a,1);
  a += __shfl_xor(a,2);
  a += __shfl_xor(a,4);
  if ((tid&7)==0) out[row] = a + wl[32];
}

extern "C" void kernel_launch(void* const* d_in, const int* in_sizes, int n_in,
                              void* d_out, int out_size, void* d_ws, size_t ws_size,
                              hipStream_t stream)
{
  (void)in_sizes; (void)n_in; (void)out_size; (void)ws_size;
  const float* customer_x = (const float*)d_in[0];
  const float* product_x  = (const float*)d_in[1];
  const float* pcW = (const float*)d_in[2];
  const float* pcB = (const float*)d_in[3];
  const float* ppW = (const float*)d_in[4];
  const float* ppB = (const float*)d_in[5];
  const float* att_src_r  = (const float*)d_in[6];
  const float* att_dst_r  = (const float*)d_in[7];
  const float* att_src_rb = (const float*)d_in[8];
  const float* att_dst_rb = (const float*)d_in[9];
  // d_in[10..12] dead (semantic softmax over 1 metapath == 1)
  const float* color_emb = (const float*)d_in[13];
  const float* size_emb  = (const float*)d_in[14];
  const float* group_emb = (const float*)d_in[15];
  const float* fc1W = (const float*)d_in[16];
  const float* fc1b = (const float*)d_in[17];
  const float* fc2W = (const float*)d_in[18];
  const float* fc2b = (const float*)d_in[19];
  const float* fc3W = (const float*)d_in[20];
  const float* fc3b = (const float*)d_in[21];
  const float* bn1g = (const float*)d_in[22];
  const float* bn1b = (const float*)d_in[23];
  const float* bn2g = (const float*)d_in[24];
  const float* bn2b = (const float*)d_in[25];
  const int* edge_src  = (const int*)d_in[26];
  const int* edge_dst  = (const int*)d_in[27];
  const int* label_src = (const int*)d_in[28];
  const int* label_dst = (const int*)d_in[29];
  const int* size_idx  = (const int*)d_in[30];
  const int* color_idx = (const int*)d_in[31];
  const int* group_idx = (const int*)d_in[32];

  char* ws = (char*)d_ws;
  size_t off = 0;
  auto alloc = [&](size_t bytes)->char* {
    char* p = ws + off;
    off += (bytes + 255) & ~(size_t)255;
    return p;
  };
  // ~234 MB peak (< 256 MiB hard limit per R1/R2 fault evidence)
  unsigned short* H_c  = (unsigned short*)alloc((size_t)NCC*256*2);   // 102.4 MB; out_c aliases after agg_r
  unsigned short* H_p  = (unsigned short*)alloc((size_t)NPRR*256*2);  // 51.2 MB; x1b aliases after agg_rb
  unsigned short* out_p= (unsigned short*)alloc((size_t)NPRR*256*2);  // 51.2 MB
  float* s_cr     = (float*)alloc((size_t)NCC*8*4);     // 6.4 MB (x2b aliases after aggs)
  float* s_crb    = (float*)alloc((size_t)NCC*8*4);     // 6.4 MB
  float* s_pr     = (float*)alloc((size_t)NPRR*8*4);    // 3.2 MB
  float* s_prb    = (float*)alloc((size_t)NPRR*8*4);    // 3.2 MB
  int* rowptr_r   = (int*)alloc((size_t)(NPRR+1)*4);
  int* rowptr_rb  = (int*)alloc((size_t)(NCC+1)*4);
  int* srcidx_r   = (int*)alloc((size_t)NEE*4);         // 2 MB
  int* srcidx_rb  = (int*)alloc((size_t)NEE*4);         // 2 MB
  // all 4 counter buffers in ONE allocation — contiguous, memset length exact (R10 fix)
  int* cnts       = (int*)alloc((size_t)(NCC+NPRR)*2*4);
  int* cnt_c      = cnts;
  int* cnt_p      = cnts + NCC;
  int* cnt_c2     = cnts + NCC + NPRR;
  int* cnt_p2     = cnts + NCC + NPRR + NCC;
  int* bsum_c     = (int*)alloc(256*4);
  int* bsum_p     = (int*)alloc(256*4);
  unsigned short* Bt = (unsigned short*)alloc(128*544*2);
  float* wa_c   = (float*)alloc(272*4);
  float* wa_p   = (float*)alloc(272*4);
  float* bnsum1 = (float*)alloc(256*4);
  float* bnsum2 = (float*)alloc(64*4);
  float* fc2p   = (float*)alloc(4096*4);
  float* b2p    = (float*)alloc(32*4);
  float* w3p    = (float*)alloc(34*4);
  unsigned short* out_c = H_c;                   // H_c dead after agg_r
  unsigned short* x1b   = H_p;                   // H_p dead after agg_rb
  unsigned short* x2b   = (unsigned short*)s_cr; // scores dead after aggs

  hipMemsetAsync(bnsum1, 0, 1280, stream);       // bnsum1+bnsum2 contiguous
  hipMemsetAsync(cnts, 0, (size_t)(NCC+NPRR)*2*4, stream);

  // WA prep (both node types), then proj+score fused per node type
  wa_prep2<<<1,256,0,stream>>>(pcW, pcB, att_src_r, att_dst_rb,
                               ppW, ppB, att_dst_r, att_src_rb, wa_c, wa_p);
  proj_kernel<<<2048,256,0,stream>>>(customer_x, pcW, pcB, wa_c, H_c, s_cr, s_crb, NCC);
  proj_kernel<<<2048,256,0,stream>>>(product_x,  ppW, ppB, wa_p, H_p, s_pr, s_prb, NPRR);

  // CSR build (both relations)
  const int eg = (NEE+255)/256;
  const int BP = (NPRR+1023)/1024;   // 98
  const int BC = (NCC +1023)/1024;   // 196
  hist2<<<eg,256,0,stream>>>(edge_src, edge_dst, cnt_c, cnt_p, NEE);
  scan_phase1<<<BP,256,0,stream>>>(cnt_p, bsum_p, NPRR);
  scan_phase2<<<1,256,0,stream>>>(bsum_p, BP, rowptr_r, NPRR);
  scan_phase3<<<BP,256,0,stream>>>(cnt_p, bsum_p, rowptr_r, NPRR);
  scan_phase1<<<BC,256,0,stream>>>(cnt_c, bsum_c, NCC);
  scan_phase2<<<1,256,0,stream>>>(bsum_c, BC, rowptr_rb, NCC);
  scan_phase3<<<BC,256,0,stream>>>(cnt_c, bsum_c, rowptr_rb, NCC);
  place2<<<eg,256,0,stream>>>(edge_src, edge_dst, rowptr_r, rowptr_rb,
      cnt_p2, cnt_c2, srcidx_r, srcidx_rb, NEE);

  // single-pass gather aggregation v2 (side-split lanes, uint4 loads)
  agg_kernel<<<(NPRR+3)/4,256,0,stream>>>(rowptr_r,  srcidx_r,  s_cr,  s_pr,  H_c, out_p, NPRR);
  agg_kernel<<<(NCC +3)/4,256,0,stream>>>(rowptr_rb, srcidx_rb, s_prb, s_crb, H_p, out_c, NCC);

  // tail MLP: MFMA fc1 (async DMA staging) + folded BN
  prep_bt<<<(128*544+255)/256,256,0,stream>>>(fc1W, Bt);
  fc1_mfma<<<NBB/32,256,0,stream>>>(out_c, out_p, size_emb, color_emb, group_emb,
      label_src, label_dst, size_idx, color_idx, group_idx, Bt, fc1b, x1b, bnsum1);
  bn1_fold<<<1,256,0,stream>>>(bnsum1, bn1g, bn1b, fc2W, fc2b, fc2p, b2p, 1.0f/NBB);
  fc2_kernel<<<NBB/64,256,0,stream>>>(x1b, fc2p, b2p, x2b, bnsum2);
  bn2_fold<<<1,64,0,stream>>>(bnsum2, bn2g, bn2b, fc3W, fc3b, w3p, 1.0f/NBB);
  fc3_kernel<<<NBB/32,256,0,stream>>>(x2b, w3p, (float*)d_out);
}